// Round 1
// baseline (1078.744 us; speedup 1.0000x reference)
//
#include <hip/hip_runtime.h>
#include <math.h>

// Problem constants (from reference): SEQ=2048, BATCH=2, D_MODEL=1024, H=16, Hd=64
#define SEQ     2048
#define BATCH   2
#define DMODEL  1024
#define NHEADS  16
#define HDIM    64
#define MROWS   (SEQ * BATCH)   // 4096 rows for all GEMMs

// ---------------------------------------------------------------------------
// GEMM (NT): C[m][n] = sum_k A[m*1024+k] * W[n*1024+k]
// M=4096, N=1024, K=1024 hard-coded (all four GEMMs share this shape).
// 128x128 tile, BK=16, 256 threads, 8x8 per thread as four 4x4 quadrants.
// LDS stores both tiles k-major (transposed) so the inner loop is pure
// outer-product with conflict-free ds_read_b128.
// ---------------------------------------------------------------------------
#define BM 128
#define BN 128
#define BK 16

__global__ __launch_bounds__(256)
void gemm_nt_kernel(const float* __restrict__ A,
                    const float* __restrict__ W,
                    float* __restrict__ C)
{
    __shared__ float a_s[BK][BM + 4];   // [k][m], pad 4 keeps float4 alignment
    __shared__ float b_s[BK][BN + 4];   // [k][n]

    const int tid = threadIdx.x;
    const int tx  = tid & 15;           // 0..15 -> n
    const int ty  = tid >> 4;           // 0..15 -> m
    const int m0  = blockIdx.y * BM;
    const int n0  = blockIdx.x * BN;

    float acc[2][2][4][4] = {};

    const int chunk = tid & 3;          // float4 index along k
    const int row   = tid >> 2;         // 0..63

    for (int k0 = 0; k0 < 1024; k0 += BK) {
        // ---- stage tiles (transpose into k-major LDS) ----
        #pragma unroll
        for (int it = 0; it < 2; ++it) {
            const int r = row + it * 64;
            const float4 fa = *reinterpret_cast<const float4*>(
                A + (size_t)(m0 + r) * 1024 + k0 + chunk * 4);
            const float4 fb = *reinterpret_cast<const float4*>(
                W + (size_t)(n0 + r) * 1024 + k0 + chunk * 4);
            a_s[chunk*4+0][r] = fa.x; a_s[chunk*4+1][r] = fa.y;
            a_s[chunk*4+2][r] = fa.z; a_s[chunk*4+3][r] = fa.w;
            b_s[chunk*4+0][r] = fb.x; b_s[chunk*4+1][r] = fb.y;
            b_s[chunk*4+2][r] = fb.z; b_s[chunk*4+3][r] = fb.w;
        }
        __syncthreads();

        // ---- outer-product inner loop ----
        #pragma unroll
        for (int kk = 0; kk < BK; ++kk) {
            const float4 a0 = *reinterpret_cast<const float4*>(&a_s[kk][ty*4]);
            const float4 a1 = *reinterpret_cast<const float4*>(&a_s[kk][ty*4 + 64]);
            const float4 b0 = *reinterpret_cast<const float4*>(&b_s[kk][tx*4]);
            const float4 b1 = *reinterpret_cast<const float4*>(&b_s[kk][tx*4 + 64]);
            const float av[2][4] = {{a0.x,a0.y,a0.z,a0.w},{a1.x,a1.y,a1.z,a1.w}};
            const float bv[2][4] = {{b0.x,b0.y,b0.z,b0.w},{b1.x,b1.y,b1.z,b1.w}};
            #pragma unroll
            for (int im = 0; im < 2; ++im)
                #pragma unroll
                for (int in2 = 0; in2 < 2; ++in2)
                    #pragma unroll
                    for (int i = 0; i < 4; ++i)
                        #pragma unroll
                        for (int j = 0; j < 4; ++j)
                            acc[im][in2][i][j] =
                                fmaf(av[im][i], bv[in2][j], acc[im][in2][i][j]);
        }
        __syncthreads();
    }

    // ---- epilogue: float4 stores ----
    #pragma unroll
    for (int im = 0; im < 2; ++im)
        #pragma unroll
        for (int i = 0; i < 4; ++i) {
            const int m = m0 + im * 64 + ty * 4 + i;
            #pragma unroll
            for (int in2 = 0; in2 < 2; ++in2) {
                const int n = n0 + in2 * 64 + tx * 4;
                const float4 o = make_float4(acc[im][in2][i][0], acc[im][in2][i][1],
                                             acc[im][in2][i][2], acc[im][in2][i][3]);
                *reinterpret_cast<float4*>(C + (size_t)m * 1024 + n) = o;
            }
        }
}

// ---------------------------------------------------------------------------
// Flash-style causal attention.
// Q/K/V buffers laid out (S*B, D) rows = s*BATCH+b; head h occupies cols
// [h*64, h*64+64). One block = 64 query rows of one (b,h); 256 threads,
// thread (ty,tx) owns a 4x4 patch. Both QK^T and PV run as outer products
// from k-major / transposed-P LDS tiles -> conflict-free b128 reads.
// ---------------------------------------------------------------------------
#define QT 64
#define KT 64

__global__ __launch_bounds__(256)
void attn_kernel(const float* __restrict__ Qb, const float* __restrict__ Kb,
                 const float* __restrict__ Vb, float* __restrict__ Ob)
{
    __shared__ float qT_s[HDIM][QT + 4];   // [d][r]
    __shared__ float kT_s[HDIM][KT + 4];   // [d][c]
    __shared__ float v_s [KT][HDIM + 4];   // [t][d]
    __shared__ float pT_s[KT][QT + 4];     // [t][r]

    const int tid = threadIdx.x;
    const int tx  = tid & 15;
    const int ty  = tid >> 4;
    const int q0  = blockIdx.x * QT;
    const int b   = blockIdx.y >> 4;       // blockIdx.y = b*16 + h
    const int h   = blockIdx.y & 15;
    const size_t cb = (size_t)h * HDIM;

    // ---- stage Q tile transposed ----
    #pragma unroll
    for (int it = 0; it < 4; ++it) {
        const int f4 = it * 256 + tid;     // 0..1023
        const int r  = f4 >> 4;            // 0..63
        const int c4 = f4 & 15;            // 0..15
        const float4 fq = *reinterpret_cast<const float4*>(
            Qb + ((size_t)(q0 + r) * BATCH + b) * DMODEL + cb + c4 * 4);
        qT_s[c4*4+0][r] = fq.x; qT_s[c4*4+1][r] = fq.y;
        qT_s[c4*4+2][r] = fq.z; qT_s[c4*4+3][r] = fq.w;
    }

    float m_r[4], l_r[4], o_r[4][4];
    #pragma unroll
    for (int i = 0; i < 4; ++i) {
        m_r[i] = -1e30f; l_r[i] = 0.f;
        #pragma unroll
        for (int j = 0; j < 4; ++j) o_r[i][j] = 0.f;
    }

    const int ktiles = blockIdx.x + 1;     // causal: k0 <= q0
    for (int kt = 0; kt < ktiles; ++kt) {
        const int k0 = kt * KT;

        // ---- stage K (transposed) and V tiles ----
        __syncthreads();   // previous iteration's PV reads done
        #pragma unroll
        for (int it = 0; it < 4; ++it) {
            const int f4 = it * 256 + tid;
            const int r  = f4 >> 4;
            const int c4 = f4 & 15;
            const size_t g = ((size_t)(k0 + r) * BATCH + b) * DMODEL + cb + c4 * 4;
            const float4 fk = *reinterpret_cast<const float4*>(Kb + g);
            kT_s[c4*4+0][r] = fk.x; kT_s[c4*4+1][r] = fk.y;
            kT_s[c4*4+2][r] = fk.z; kT_s[c4*4+3][r] = fk.w;
            const float4 fv = *reinterpret_cast<const float4*>(Vb + g);
            *reinterpret_cast<float4*>(&v_s[r][c4 * 4]) = fv;
        }
        __syncthreads();

        // ---- S = Q K^T (outer product over d) ----
        float s[4][4] = {};
        #pragma unroll 8
        for (int kk = 0; kk < HDIM; ++kk) {
            const float4 qv = *reinterpret_cast<const float4*>(&qT_s[kk][ty*4]);
            const float4 kv = *reinterpret_cast<const float4*>(&kT_s[kk][tx*4]);
            const float qa[4] = {qv.x, qv.y, qv.z, qv.w};
            const float ka[4] = {kv.x, kv.y, kv.z, kv.w};
            #pragma unroll
            for (int i = 0; i < 4; ++i)
                #pragma unroll
                for (int j = 0; j < 4; ++j)
                    s[i][j] = fmaf(qa[i], ka[j], s[i][j]);
        }

        // ---- mask, online softmax update ----
        const float scale = 0.125f;  // 1/sqrt(64)
        float alpha[4];
        #pragma unroll
        for (int i = 0; i < 4; ++i) {
            const int qi = q0 + ty * 4 + i;
            float rmax = -1e30f;
            #pragma unroll
            for (int j = 0; j < 4; ++j) {
                const int kj = k0 + tx * 4 + j;
                s[i][j] = (kj <= qi) ? s[i][j] * scale : -1e30f;
                rmax = fmaxf(rmax, s[i][j]);
            }
            #pragma unroll
            for (int off = 1; off < 16; off <<= 1)
                rmax = fmaxf(rmax, __shfl_xor(rmax, off));
            const float mnew = fmaxf(m_r[i], rmax);
            alpha[i] = __expf(m_r[i] - mnew);   // first tile: exp(-1e30-..)=0, no NaN
            m_r[i] = mnew;
            float rs = 0.f;
            #pragma unroll
            for (int j = 0; j < 4; ++j) {
                s[i][j] = __expf(s[i][j] - mnew);  // masked -> exp(-1e30) = 0
                rs += s[i][j];
            }
            #pragma unroll
            for (int off = 1; off < 16; off <<= 1)
                rs += __shfl_xor(rs, off);
            l_r[i] = l_r[i] * alpha[i] + rs;
            #pragma unroll
            for (int j = 0; j < 4; ++j) o_r[i][j] *= alpha[i];
        }

        // ---- write P transposed: pT_s[t][r] ----
        #pragma unroll
        for (int j = 0; j < 4; ++j) {
            const float4 pv = make_float4(s[0][j], s[1][j], s[2][j], s[3][j]);
            *reinterpret_cast<float4*>(&pT_s[tx*4 + j][ty*4]) = pv;
        }
        __syncthreads();

        // ---- O += P V (outer product over t) ----
        #pragma unroll 8
        for (int t = 0; t < KT; ++t) {
            const float4 pv4 = *reinterpret_cast<const float4*>(&pT_s[t][ty*4]);
            const float4 vv4 = *reinterpret_cast<const float4*>(&v_s[t][tx*4]);
            const float pa[4] = {pv4.x, pv4.y, pv4.z, pv4.w};
            const float va[4] = {vv4.x, vv4.y, vv4.z, vv4.w};
            #pragma unroll
            for (int i = 0; i < 4; ++i)
                #pragma unroll
                for (int j = 0; j < 4; ++j)
                    o_r[i][j] = fmaf(pa[i], va[j], o_r[i][j]);
        }
    }

    // ---- normalize and store ----
    #pragma unroll
    for (int i = 0; i < 4; ++i) {
        const float inv = 1.0f / l_r[i];
        const int qi = q0 + ty * 4 + i;
        const float4 o = make_float4(o_r[i][0] * inv, o_r[i][1] * inv,
                                     o_r[i][2] * inv, o_r[i][3] * inv);
        *reinterpret_cast<float4*>(
            Ob + ((size_t)qi * BATCH + b) * DMODEL + cb + tx * 4) = o;
    }
}

// ---------------------------------------------------------------------------
extern "C" void kernel_launch(void* const* d_in, const int* in_sizes, int n_in,
                              void* d_out, int out_size, void* d_ws, size_t ws_size,
                              hipStream_t stream) {
    const float* x  = (const float*)d_in[0];
    const float* Wq = (const float*)d_in[1];
    const float* Wk = (const float*)d_in[2];
    const float* Wv = (const float*)d_in[3];
    const float* Wo = (const float*)d_in[4];
    float* out = (float*)d_out;

    const size_t NELEM = (size_t)MROWS * DMODEL;   // 4M floats = 16 MB
    float* Qb = (float*)d_ws;
    float* Kb = Qb + NELEM;
    float* Vb = Kb + NELEM;
    float* Ab = Vb + NELEM;    // attention output, pre-projection

    const dim3 gemm_grid(DMODEL / BN, MROWS / BM);   // (8, 32)
    gemm_nt_kernel<<<gemm_grid, 256, 0, stream>>>(x, Wq, Qb);
    gemm_nt_kernel<<<gemm_grid, 256, 0, stream>>>(x, Wk, Kb);
    gemm_nt_kernel<<<gemm_grid, 256, 0, stream>>>(x, Wv, Vb);

    const dim3 attn_grid(SEQ / QT, BATCH * NHEADS); // (32, 32)
    attn_kernel<<<attn_grid, 256, 0, stream>>>(Qb, Kb, Vb, Ab);

    gemm_nt_kernel<<<gemm_grid, 256, 0, stream>>>(Ab, Wo, out);
}

// Round 3
// 738.865 us; speedup vs baseline: 1.4600x; 1.4600x over previous
//
#include <hip/hip_runtime.h>
#include <math.h>

// Problem constants: SEQ=2048, BATCH=2, D_MODEL=1024, H=16, Hd=64
#define SEQ     2048
#define BATCH   2
#define DMODEL  1024
#define NHEADS  16
#define HDIM    64
#define MROWS   (SEQ * BATCH)   // 4096 rows for all GEMMs
#define KDIM    1024

typedef _Float16 half8 __attribute__((ext_vector_type(8)));
typedef float    f32x4 __attribute__((ext_vector_type(4)));

// ---------------------------------------------------------------------------
// async global->LDS, 16B per lane. dest must be wave-uniform; HW adds lane*16.
// ---------------------------------------------------------------------------
__device__ inline void gload_lds16(const void* g, void* lds_uniform) {
    __builtin_amdgcn_global_load_lds(
        (const __attribute__((address_space(1))) void*)g,
        (__attribute__((address_space(3))) void*)lds_uniform,
        16, 0, 0);
}

// ---------------------------------------------------------------------------
// fp32 -> f16 conversion (weights only; 1M elems per launch, 8 per thread)
// ---------------------------------------------------------------------------
__global__ __launch_bounds__(256)
void cvt_f32_f16(const float* __restrict__ s, _Float16* __restrict__ d, int n8) {
    const int i = blockIdx.x * 256 + threadIdx.x;
    if (i < n8) {
        const float4* sp = reinterpret_cast<const float4*>(s) + (size_t)i * 2;
        const float4 x0 = sp[0], x1 = sp[1];
        const half8 h = {(_Float16)x0.x, (_Float16)x0.y, (_Float16)x0.z, (_Float16)x0.w,
                         (_Float16)x1.x, (_Float16)x1.y, (_Float16)x1.z, (_Float16)x1.w};
        *(reinterpret_cast<half8*>(d) + i) = h;
    }
}

// ---------------------------------------------------------------------------
// C[m][n] = sum_k A[m][k] * W[n][k]   (A fp32 in memory, W pre-converted f16)
// M=4096, N=1024, K=1024. BM=128, BN=64, BK=32 -> grid (16,32)=512 blocks.
// 256 threads = 4 waves as 2x2; each wave owns 64x32 out = 4x2 frags of 16x16.
// A: reg-staged (load f32, cvt f16, ds_write_b128, conflict-free linear order).
// W: global_load_lds width 16 straight into LDS (B^T layout: K contiguous).
// mfma_f32_16x16x32_f16: A-frag lane l -> row l&15, k (l>>4)*8+j; B same with
// col=l&15. C/D: col=lane&15, row=(lane>>4)*4+reg  [m89-verified mapping].
// ---------------------------------------------------------------------------
#define GBM 128
#define GBN 64
#define GBK 32

__global__ __launch_bounds__(256)
void gemm_a32_w16(const float* __restrict__ A, const _Float16* __restrict__ Wh,
                  float* __restrict__ C)
{
    __shared__ _Float16 As[GBM * GBK];   // [128][32] f16 = 8 KB, row-major
    __shared__ _Float16 Bs[GBN * GBK];   // [64][32]  f16 = 4 KB

    const int tid  = threadIdx.x;
    const int wid  = tid >> 6;
    const int lane = tid & 63;
    const int m0 = blockIdx.y * GBM;
    const int n0 = blockIdx.x * GBN;
    const int wr = (wid >> 1) * 64;      // wave row offset in tile
    const int wc = (wid & 1) * 32;       // wave col offset in tile

    // A staging: chunk c in {0,1}: LDS byte o = c*4096 + tid*16
    //   -> row = c*64 + (tid>>2), elem col = (tid&3)*8  (8 f16 = 16B)
    const int a_row = tid >> 2;
    const int a_col = (tid & 3) * 8;
    // B staging: wave-issue: LDS byte o = wid*1024 + lane*16
    //   -> row = wid*16 + (lane>>2), elem col = (lane&3)*8
    const int b_row = wid * 16 + (lane >> 2);
    const int b_col = (lane & 3) * 8;

    const float*    Ar0 = A  + (size_t)(m0 + a_row)      * KDIM + a_col;
    const float*    Ar1 = A  + (size_t)(m0 + a_row + 64) * KDIM + a_col;
    const _Float16* Wr  = Wh + (size_t)(n0 + b_row)      * KDIM + b_col;

    const int frow = lane & 15;          // fragment row (A) / col (B)
    const int kb   = (lane >> 4) * 8;    // k sub-slice

    f32x4 acc[4][2] = {};

    for (int k0 = 0; k0 < KDIM; k0 += GBK) {
        // ---- stage B tile via async direct-to-LDS ----
        gload_lds16(Wr + k0, (char*)Bs + wid * 1024);

        // ---- stage A tile: f32 loads -> f16 -> conflict-free b128 writes ----
        const float4 a0 = *reinterpret_cast<const float4*>(Ar0 + k0);
        const float4 a1 = *reinterpret_cast<const float4*>(Ar0 + k0 + 4);
        const float4 a2 = *reinterpret_cast<const float4*>(Ar1 + k0);
        const float4 a3 = *reinterpret_cast<const float4*>(Ar1 + k0 + 4);
        const half8 h0 = {(_Float16)a0.x, (_Float16)a0.y, (_Float16)a0.z, (_Float16)a0.w,
                          (_Float16)a1.x, (_Float16)a1.y, (_Float16)a1.z, (_Float16)a1.w};
        const half8 h1 = {(_Float16)a2.x, (_Float16)a2.y, (_Float16)a2.z, (_Float16)a2.w,
                          (_Float16)a3.x, (_Float16)a3.y, (_Float16)a3.z, (_Float16)a3.w};
        *reinterpret_cast<half8*>((char*)As + tid * 16)        = h0;
        *reinterpret_cast<half8*>((char*)As + 4096 + tid * 16) = h1;

        __syncthreads();   // drains vmcnt (gload_lds) + lgkmcnt (ds_write)

        // ---- fragments + MFMA ----
        half8 af[4], bf[2];
        #pragma unroll
        for (int fm = 0; fm < 4; ++fm)
            af[fm] = *reinterpret_cast<const half8*>(&As[(wr + fm * 16 + frow) * GBK + kb]);
        #pragma unroll
        for (int fn = 0; fn < 2; ++fn)
            bf[fn] = *reinterpret_cast<const half8*>(&Bs[(wc + fn * 16 + frow) * GBK + kb]);
        #pragma unroll
        for (int fm = 0; fm < 4; ++fm)
            #pragma unroll
            for (int fn = 0; fn < 2; ++fn)
                acc[fm][fn] = __builtin_amdgcn_mfma_f32_16x16x32_f16(
                    af[fm], bf[fn], acc[fm][fn], 0, 0, 0);

        __syncthreads();   // protect LDS before next stage
    }

    // ---- epilogue: C[row][col], col = lane&15, row = (lane>>4)*4 + r ----
    const int crow = (lane >> 4) * 4;
    const int ccol = lane & 15;
    #pragma unroll
    for (int fm = 0; fm < 4; ++fm)
        #pragma unroll
        for (int fn = 0; fn < 2; ++fn)
            #pragma unroll
            for (int r = 0; r < 4; ++r)
                C[(size_t)(m0 + wr + fm * 16 + crow + r) * DMODEL
                  + n0 + wc + fn * 16 + ccol] = acc[fm][fn][r];
}

// ---------------------------------------------------------------------------
// Flash-style causal attention (UNCHANGED — fp32).
// ---------------------------------------------------------------------------
#define QT 64
#define KT 64

__global__ __launch_bounds__(256)
void attn_kernel(const float* __restrict__ Qb, const float* __restrict__ Kb,
                 const float* __restrict__ Vb, float* __restrict__ Ob)
{
    __shared__ float qT_s[HDIM][QT + 4];   // [d][r]
    __shared__ float kT_s[HDIM][KT + 4];   // [d][c]
    __shared__ float v_s [KT][HDIM + 4];   // [t][d]
    __shared__ float pT_s[KT][QT + 4];     // [t][r]

    const int tid = threadIdx.x;
    const int tx  = tid & 15;
    const int ty  = tid >> 4;
    const int q0  = blockIdx.x * QT;
    const int b   = blockIdx.y >> 4;
    const int h   = blockIdx.y & 15;
    const size_t cb = (size_t)h * HDIM;

    #pragma unroll
    for (int it = 0; it < 4; ++it) {
        const int f4 = it * 256 + tid;
        const int r  = f4 >> 4;
        const int c4 = f4 & 15;
        const float4 fq = *reinterpret_cast<const float4*>(
            Qb + ((size_t)(q0 + r) * BATCH + b) * DMODEL + cb + c4 * 4);
        qT_s[c4*4+0][r] = fq.x; qT_s[c4*4+1][r] = fq.y;
        qT_s[c4*4+2][r] = fq.z; qT_s[c4*4+3][r] = fq.w;
    }

    float m_r[4], l_r[4], o_r[4][4];
    #pragma unroll
    for (int i = 0; i < 4; ++i) {
        m_r[i] = -1e30f; l_r[i] = 0.f;
        #pragma unroll
        for (int j = 0; j < 4; ++j) o_r[i][j] = 0.f;
    }

    const int ktiles = blockIdx.x + 1;
    for (int kt = 0; kt < ktiles; ++kt) {
        const int k0 = kt * KT;

        __syncthreads();
        #pragma unroll
        for (int it = 0; it < 4; ++it) {
            const int f4 = it * 256 + tid;
            const int r  = f4 >> 4;
            const int c4 = f4 & 15;
            const size_t g = ((size_t)(k0 + r) * BATCH + b) * DMODEL + cb + c4 * 4;
            const float4 fk = *reinterpret_cast<const float4*>(Kb + g);
            kT_s[c4*4+0][r] = fk.x; kT_s[c4*4+1][r] = fk.y;
            kT_s[c4*4+2][r] = fk.z; kT_s[c4*4+3][r] = fk.w;
            const float4 fv = *reinterpret_cast<const float4*>(Vb + g);
            *reinterpret_cast<float4*>(&v_s[r][c4 * 4]) = fv;
        }
        __syncthreads();

        float s[4][4] = {};
        #pragma unroll 8
        for (int kk = 0; kk < HDIM; ++kk) {
            const float4 qv = *reinterpret_cast<const float4*>(&qT_s[kk][ty*4]);
            const float4 kv = *reinterpret_cast<const float4*>(&kT_s[kk][tx*4]);
            const float qa[4] = {qv.x, qv.y, qv.z, qv.w};
            const float ka[4] = {kv.x, kv.y, kv.z, kv.w};
            #pragma unroll
            for (int i = 0; i < 4; ++i)
                #pragma unroll
                for (int j = 0; j < 4; ++j)
                    s[i][j] = fmaf(qa[i], ka[j], s[i][j]);
        }

        const float scale = 0.125f;
        float alpha[4];
        #pragma unroll
        for (int i = 0; i < 4; ++i) {
            const int qi = q0 + ty * 4 + i;
            float rmax = -1e30f;
            #pragma unroll
            for (int j = 0; j < 4; ++j) {
                const int kj = k0 + tx * 4 + j;
                s[i][j] = (kj <= qi) ? s[i][j] * scale : -1e30f;
                rmax = fmaxf(rmax, s[i][j]);
            }
            #pragma unroll
            for (int off = 1; off < 16; off <<= 1)
                rmax = fmaxf(rmax, __shfl_xor(rmax, off));
            const float mnew = fmaxf(m_r[i], rmax);
            alpha[i] = __expf(m_r[i] - mnew);
            m_r[i] = mnew;
            float rs = 0.f;
            #pragma unroll
            for (int j = 0; j < 4; ++j) {
                s[i][j] = __expf(s[i][j] - mnew);
                rs += s[i][j];
            }
            #pragma unroll
            for (int off = 1; off < 16; off <<= 1)
                rs += __shfl_xor(rs, off);
            l_r[i] = l_r[i] * alpha[i] + rs;
            #pragma unroll
            for (int j = 0; j < 4; ++j) o_r[i][j] *= alpha[i];
        }

        #pragma unroll
        for (int j = 0; j < 4; ++j) {
            const float4 pv = make_float4(s[0][j], s[1][j], s[2][j], s[3][j]);
            *reinterpret_cast<float4*>(&pT_s[tx*4 + j][ty*4]) = pv;
        }
        __syncthreads();

        #pragma unroll 8
        for (int t = 0; t < KT; ++t) {
            const float4 pv4 = *reinterpret_cast<const float4*>(&pT_s[t][ty*4]);
            const float4 vv4 = *reinterpret_cast<const float4*>(&v_s[t][tx*4]);
            const float pa[4] = {pv4.x, pv4.y, pv4.z, pv4.w};
            const float va[4] = {vv4.x, vv4.y, vv4.z, vv4.w};
            #pragma unroll
            for (int i = 0; i < 4; ++i)
                #pragma unroll
                for (int j = 0; j < 4; ++j)
                    o_r[i][j] = fmaf(pa[i], va[j], o_r[i][j]);
        }
    }

    #pragma unroll
    for (int i = 0; i < 4; ++i) {
        const float inv = 1.0f / l_r[i];
        const int qi = q0 + ty * 4 + i;
        const float4 o = make_float4(o_r[i][0] * inv, o_r[i][1] * inv,
                                     o_r[i][2] * inv, o_r[i][3] * inv);
        *reinterpret_cast<float4*>(
            Ob + ((size_t)qi * BATCH + b) * DMODEL + cb + tx * 4) = o;
    }
}

// ---------------------------------------------------------------------------
// ws layout (72 MB):
//   Qb f32 16MB | Kb f32 16MB | Vb f32 16MB | Ab f32 16MB | Wh f16 4x2MB
// ---------------------------------------------------------------------------
extern "C" void kernel_launch(void* const* d_in, const int* in_sizes, int n_in,
                              void* d_out, int out_size, void* d_ws, size_t ws_size,
                              hipStream_t stream) {
    const float* x  = (const float*)d_in[0];
    const float* Wq = (const float*)d_in[1];
    const float* Wk = (const float*)d_in[2];
    const float* Wv = (const float*)d_in[3];
    const float* Wo = (const float*)d_in[4];
    float* out = (float*)d_out;

    const size_t NELEM = (size_t)MROWS * DMODEL;       // 4M
    const size_t WELEM = (size_t)DMODEL * DMODEL;      // 1M
    float* Qb = (float*)d_ws;
    float* Kb = Qb + NELEM;
    float* Vb = Kb + NELEM;
    float* Ab = Vb + NELEM;
    _Float16* Wh = (_Float16*)(Ab + NELEM);

    // ---- weight conversion pre-pass (f32 -> f16) ----
    const int wn8 = (int)(WELEM / 8);                  // 131072
    const int cvt_blocks = (wn8 + 255) / 256;
    cvt_f32_f16<<<cvt_blocks, 256, 0, stream>>>(Wq, Wh + 0 * WELEM, wn8);
    cvt_f32_f16<<<cvt_blocks, 256, 0, stream>>>(Wk, Wh + 1 * WELEM, wn8);
    cvt_f32_f16<<<cvt_blocks, 256, 0, stream>>>(Wv, Wh + 2 * WELEM, wn8);
    cvt_f32_f16<<<cvt_blocks, 256, 0, stream>>>(Wo, Wh + 3 * WELEM, wn8);

    // ---- projections: f16 MFMA GEMMs ----
    const dim3 ggrid(DMODEL / GBN, MROWS / GBM);       // (16, 32) = 512 blocks
    gemm_a32_w16<<<ggrid, 256, 0, stream>>>(x, Wh + 0 * WELEM, Qb);
    gemm_a32_w16<<<ggrid, 256, 0, stream>>>(x, Wh + 1 * WELEM, Kb);
    gemm_a32_w16<<<ggrid, 256, 0, stream>>>(x, Wh + 2 * WELEM, Vb);

    // ---- attention (fp32, unchanged) ----
    const dim3 attn_grid(SEQ / QT, BATCH * NHEADS);    // (32, 32)
    attn_kernel<<<attn_grid, 256, 0, stream>>>(Qb, Kb, Vb, Ab);

    // ---- output projection ----
    gemm_a32_w16<<<ggrid, 256, 0, stream>>>(Ab, Wh + 3 * WELEM, out);
}

// Round 4
// 319.416 us; speedup vs baseline: 3.3772x; 2.3132x over previous
//
#include <hip/hip_runtime.h>
#include <math.h>

// Problem constants: SEQ=2048, BATCH=2, D_MODEL=1024, H=16, Hd=64
#define SEQ     2048
#define BATCH   2
#define DMODEL  1024
#define NHEADS  16
#define HDIM    64
#define MROWS   (SEQ * BATCH)   // 4096 rows for all GEMMs
#define KDIM    1024

typedef _Float16 half8  __attribute__((ext_vector_type(8)));
typedef _Float16 half2v __attribute__((ext_vector_type(2)));
typedef float    f32x4  __attribute__((ext_vector_type(4)));

// ---------------------------------------------------------------------------
// async global->LDS, 16B per lane. LDS dest = wave-uniform base + lane*16.
// ---------------------------------------------------------------------------
__device__ inline void gload_lds16(const void* g, void* lds_uniform) {
    __builtin_amdgcn_global_load_lds(
        (const __attribute__((address_space(1))) void*)g,
        (__attribute__((address_space(3))) void*)lds_uniform,
        16, 0, 0);
}

// ---------------------------------------------------------------------------
// fp32 -> f16 conversion (weights; 1M elems per launch, 8 per thread)
// ---------------------------------------------------------------------------
__global__ __launch_bounds__(256)
void cvt_f32_f16(const float* __restrict__ s, _Float16* __restrict__ d, int n8) {
    const int i = blockIdx.x * 256 + threadIdx.x;
    if (i < n8) {
        const float4* sp = reinterpret_cast<const float4*>(s) + (size_t)i * 2;
        const float4 x0 = sp[0], x1 = sp[1];
        const half8 h = {(_Float16)x0.x, (_Float16)x0.y, (_Float16)x0.z, (_Float16)x0.w,
                         (_Float16)x1.x, (_Float16)x1.y, (_Float16)x1.z, (_Float16)x1.w};
        *(reinterpret_cast<half8*>(d) + i) = h;
    }
}

// ---------------------------------------------------------------------------
// GEMM: C[m][n] = sum_k A[m][k] * W[n][k].  M=4096, N=1024, K=1024.
// BM=128 BN=64 BK=32, 256 threads = 4 waves (2x2), wave: 64x32 out.
// AMODE: 0 = A fp32 (reg-stage + cvt), 1 = A f16 (reg-stage direct).
// OMODE: 0 = f32 rows, 1 = f16 rows, 2 = f16 transposed V -> Vt[b][h][d][s].
// mfma_f32_16x16x32_f16 layouts (m89-verified): A: row=l&15, k=(l>>4)*8+j;
// B: col=l&15, k=(l>>4)*8+j; C/D: col=l&15, row=(l>>4)*4+reg.
// ---------------------------------------------------------------------------
#define GBM 128
#define GBN 64
#define GBK 32

template<int AMODE, int OMODE>
__global__ __launch_bounds__(256)
void gemm_k(const void* __restrict__ Ap, const _Float16* __restrict__ Wh,
            void* __restrict__ Cp)
{
    __shared__ _Float16 As[GBM * GBK];   // 8 KB
    __shared__ _Float16 Bs[GBN * GBK];   // 4 KB

    const int tid  = threadIdx.x;
    const int wid  = tid >> 6;
    const int lane = tid & 63;
    const int m0 = blockIdx.y * GBM;
    const int n0 = blockIdx.x * GBN;
    const int wr = (wid >> 1) * 64;
    const int wc = (wid & 1) * 32;

    const int a_row = tid >> 2;
    const int a_col = (tid & 3) * 8;          // f16 elems (16B)
    const int b_row = wid * 16 + (lane >> 2);
    const int b_col = (lane & 3) * 8;

    const float*    Af0 = (const float*)Ap    + (size_t)(m0 + a_row)      * KDIM + a_col;
    const float*    Af1 = (const float*)Ap    + (size_t)(m0 + a_row + 64) * KDIM + a_col;
    const _Float16* Ah0 = (const _Float16*)Ap + (size_t)(m0 + a_row)      * KDIM + a_col;
    const _Float16* Ah1 = (const _Float16*)Ap + (size_t)(m0 + a_row + 64) * KDIM + a_col;
    const _Float16* Wr  = Wh + (size_t)(n0 + b_row) * KDIM + b_col;

    const int frow = lane & 15;
    const int kb   = (lane >> 4) * 8;

    f32x4 acc[4][2] = {};

    for (int k0 = 0; k0 < KDIM; k0 += GBK) {
        gload_lds16(Wr + k0, (char*)Bs + wid * 1024);

        if constexpr (AMODE == 0) {
            const float4 a0 = *reinterpret_cast<const float4*>(Af0 + k0);
            const float4 a1 = *reinterpret_cast<const float4*>(Af0 + k0 + 4);
            const float4 a2 = *reinterpret_cast<const float4*>(Af1 + k0);
            const float4 a3 = *reinterpret_cast<const float4*>(Af1 + k0 + 4);
            const half8 h0 = {(_Float16)a0.x, (_Float16)a0.y, (_Float16)a0.z, (_Float16)a0.w,
                              (_Float16)a1.x, (_Float16)a1.y, (_Float16)a1.z, (_Float16)a1.w};
            const half8 h1 = {(_Float16)a2.x, (_Float16)a2.y, (_Float16)a2.z, (_Float16)a2.w,
                              (_Float16)a3.x, (_Float16)a3.y, (_Float16)a3.z, (_Float16)a3.w};
            *reinterpret_cast<half8*>((char*)As + tid * 16)        = h0;
            *reinterpret_cast<half8*>((char*)As + 4096 + tid * 16) = h1;
        } else {
            const half8 h0 = *reinterpret_cast<const half8*>(Ah0 + k0);
            const half8 h1 = *reinterpret_cast<const half8*>(Ah1 + k0);
            *reinterpret_cast<half8*>((char*)As + tid * 16)        = h0;
            *reinterpret_cast<half8*>((char*)As + 4096 + tid * 16) = h1;
        }

        __syncthreads();

        half8 af[4], bf[2];
        #pragma unroll
        for (int fm = 0; fm < 4; ++fm)
            af[fm] = *reinterpret_cast<const half8*>(&As[(wr + fm * 16 + frow) * GBK + kb]);
        #pragma unroll
        for (int fn = 0; fn < 2; ++fn)
            bf[fn] = *reinterpret_cast<const half8*>(&Bs[(wc + fn * 16 + frow) * GBK + kb]);
        #pragma unroll
        for (int fm = 0; fm < 4; ++fm)
            #pragma unroll
            for (int fn = 0; fn < 2; ++fn)
                acc[fm][fn] = __builtin_amdgcn_mfma_f32_16x16x32_f16(
                    af[fm], bf[fn], acc[fm][fn], 0, 0, 0);

        __syncthreads();
    }

    const int crow = (lane >> 4) * 4;
    const int ccol = lane & 15;
    if constexpr (OMODE == 0) {
        float* C = (float*)Cp;
        #pragma unroll
        for (int fm = 0; fm < 4; ++fm)
            #pragma unroll
            for (int fn = 0; fn < 2; ++fn)
                #pragma unroll
                for (int r = 0; r < 4; ++r)
                    C[(size_t)(m0 + wr + fm * 16 + crow + r) * DMODEL
                      + n0 + wc + fn * 16 + ccol] = acc[fm][fn][r];
    } else if constexpr (OMODE == 1) {
        _Float16* C = (_Float16*)Cp;
        #pragma unroll
        for (int fm = 0; fm < 4; ++fm)
            #pragma unroll
            for (int fn = 0; fn < 2; ++fn)
                #pragma unroll
                for (int r = 0; r < 4; ++r)
                    C[(size_t)(m0 + wr + fm * 16 + crow + r) * DMODEL
                      + n0 + wc + fn * 16 + ccol] = (_Float16)acc[fm][fn][r];
    } else {
        // V transpose: m = s*2+b (crow even => b = r&1, s = s0 + (r>>1)).
        // Vt[((b*16+h)*64 + d)*2048 + s]; h = blockIdx.x since GBN==64.
        _Float16* Vt = (_Float16*)Cp;
        const int hh = blockIdx.x;
        #pragma unroll
        for (int fm = 0; fm < 4; ++fm)
            #pragma unroll
            for (int fn = 0; fn < 2; ++fn) {
                const int d  = wc + fn * 16 + ccol;
                const int s0 = (m0 + wr + fm * 16 + crow) >> 1;
                const half2v lo = {(_Float16)acc[fm][fn][0], (_Float16)acc[fm][fn][2]};
                const half2v hi = {(_Float16)acc[fm][fn][1], (_Float16)acc[fm][fn][3]};
                *reinterpret_cast<half2v*>(Vt + ((size_t)((0 + hh) * 64 + d)) * SEQ + s0) = lo;
                *reinterpret_cast<half2v*>(Vt + ((size_t)((16 * 16) + 0) * 0 /*unused*/ +
                    ((size_t)((16 + hh) * 64 + d)) * SEQ + s0)) = hi;
            }
    }
}

// ---------------------------------------------------------------------------
// MFMA flash attention. Grid (32 qtiles, 32 bh), 256 threads = 4 waves.
// Wave w owns q-rows [q0 + w*16, +16). KV tiles of 64.
// LDS tiles Q/K [row][64d] and Vt [d][64t], 128B rows, XOR-swizzled at 16B
// granularity (chunk ^= row&7) via pre-swizzled global_load_lds source.
// P goes through per-wave padded LDS (pitch 72 f16) — no barrier needed.
// ---------------------------------------------------------------------------
__global__ __launch_bounds__(256)
void attn_mfma(const _Float16* __restrict__ Qh, const _Float16* __restrict__ Kh,
               const _Float16* __restrict__ Vt, _Float16* __restrict__ Ab)
{
    __shared__ _Float16 Qs[64 * 64];      // 8 KB
    __shared__ _Float16 Ks[64 * 64];      // 8 KB
    __shared__ _Float16 Vs[64 * 64];      // 8 KB (rows = d, cols = t)
    __shared__ _Float16 Ps[4 * 16 * 72];  // 9 KB, per-wave P (pitch 144B)

    const int tid  = threadIdx.x;
    const int wid  = tid >> 6;
    const int lane = tid & 63;
    const int l4 = lane & 15, lg = lane >> 4;
    const int q0 = blockIdx.x * 64;
    const int bh = blockIdx.y, b = bh >> 4, h = bh & 15;

    // ---- stage Q (pre-swizzled source) ----
    #pragma unroll
    for (int i = 0; i < 2; ++i) {
        const int row = i * 32 + wid * 8 + (lane >> 3);
        const int c   = (lane & 7) ^ (row & 7);
        gload_lds16(Qh + ((size_t)((q0 + row) * 2 + b)) * DMODEL + h * 64 + c * 8,
                    (char*)Qs + i * 4096 + wid * 1024);
    }
    __syncthreads();

    half8 qf[2];
    {
        const int row = wid * 16 + l4;
        #pragma unroll
        for (int ks = 0; ks < 2; ++ks) {
            const int p = (ks * 4 + lg) ^ (row & 7);
            qf[ks] = *reinterpret_cast<const half8*>((char*)Qs + row * 128 + p * 16);
        }
    }

    float m_r[4], l_r[4];
    f32x4 o[4] = {};
    #pragma unroll
    for (int r = 0; r < 4; ++r) { m_r[r] = -1e30f; l_r[r] = 0.f; }

    _Float16* Pw = Ps + wid * 16 * 72;
    const int ktiles = blockIdx.x + 1;

    for (int kt = 0; kt < ktiles; ++kt) {
        const int t0 = kt * 64;
        __syncthreads();   // prev tile's LDS reads complete before restage
        #pragma unroll
        for (int i = 0; i < 2; ++i) {
            const int row = i * 32 + wid * 8 + (lane >> 3);
            const int c   = (lane & 7) ^ (row & 7);
            gload_lds16(Kh + ((size_t)((t0 + row) * 2 + b)) * DMODEL + h * 64 + c * 8,
                        (char*)Ks + i * 4096 + wid * 1024);
            gload_lds16(Vt + ((size_t)(bh * 64 + row)) * SEQ + t0 + c * 8,
                        (char*)Vs + i * 4096 + wid * 1024);
        }
        __syncthreads();

        // ---- S = Q K^T ----
        f32x4 sacc[4] = {};
        #pragma unroll
        for (int ks = 0; ks < 2; ++ks)
            #pragma unroll
            for (int fn = 0; fn < 4; ++fn) {
                const int row = fn * 16 + l4;
                const int p   = (ks * 4 + lg) ^ (row & 7);
                const half8 bf = *reinterpret_cast<const half8*>((char*)Ks + row * 128 + p * 16);
                sacc[fn] = __builtin_amdgcn_mfma_f32_16x16x32_f16(qf[ks], bf, sacc[fn], 0, 0, 0);
            }

        // ---- mask + online softmax (16-lane shfl reduce) ----
        const int qbase = q0 + wid * 16 + lg * 4;
        float sv[4][4];
        #pragma unroll
        for (int fn = 0; fn < 4; ++fn) {
            const int tg = t0 + fn * 16 + l4;
            #pragma unroll
            for (int r = 0; r < 4; ++r)
                sv[fn][r] = (tg <= qbase + r) ? sacc[fn][r] * 0.125f : -1e30f;
        }
        #pragma unroll
        for (int r = 0; r < 4; ++r) {
            float rm = fmaxf(fmaxf(sv[0][r], sv[1][r]), fmaxf(sv[2][r], sv[3][r]));
            rm = fmaxf(rm, __shfl_xor(rm, 1));
            rm = fmaxf(rm, __shfl_xor(rm, 2));
            rm = fmaxf(rm, __shfl_xor(rm, 4));
            rm = fmaxf(rm, __shfl_xor(rm, 8));
            const float mnew  = fmaxf(m_r[r], rm);
            const float alpha = __expf(m_r[r] - mnew);
            m_r[r] = mnew;
            float rs = 0.f;
            #pragma unroll
            for (int fn = 0; fn < 4; ++fn) {
                const float pv = __expf(sv[fn][r] - mnew);
                sv[fn][r] = pv; rs += pv;
            }
            rs += __shfl_xor(rs, 1); rs += __shfl_xor(rs, 2);
            rs += __shfl_xor(rs, 4); rs += __shfl_xor(rs, 8);
            l_r[r] = l_r[r] * alpha + rs;
            #pragma unroll
            for (int fn = 0; fn < 4; ++fn) o[fn][r] *= alpha;
        }

        // ---- P -> f16 via per-wave LDS (padded pitch, conflict-light) ----
        #pragma unroll
        for (int fn = 0; fn < 4; ++fn)
            #pragma unroll
            for (int r = 0; r < 4; ++r)
                Pw[(lg * 4 + r) * 72 + fn * 16 + l4] = (_Float16)sv[fn][r];

        half8 pf[2];
        #pragma unroll
        for (int ks = 0; ks < 2; ++ks)
            pf[ks] = *reinterpret_cast<const half8*>((char*)Pw + l4 * 144 + ks * 64 + lg * 16);

        // ---- O += P V ----
        #pragma unroll
        for (int ks = 0; ks < 2; ++ks)
            #pragma unroll
            for (int fn = 0; fn < 4; ++fn) {
                const int row = fn * 16 + l4;
                const int p   = (ks * 4 + lg) ^ (row & 7);
                const half8 vf = *reinterpret_cast<const half8*>((char*)Vs + row * 128 + p * 16);
                o[fn] = __builtin_amdgcn_mfma_f32_16x16x32_f16(pf[ks], vf, o[fn], 0, 0, 0);
            }
    }

    // ---- normalize, store f16 rows ----
    #pragma unroll
    for (int r = 0; r < 4; ++r) {
        const float inv = 1.0f / l_r[r];
        const size_t mrow = (size_t)((q0 + wid * 16 + lg * 4 + r) * 2 + b);
        #pragma unroll
        for (int fn = 0; fn < 4; ++fn)
            Ab[mrow * DMODEL + h * 64 + fn * 16 + l4] = (_Float16)(o[fn][r] * inv);
    }
}

// ---------------------------------------------------------------------------
// ws layout (40 MB): Qh 8 | Kh 8 | Vt 8 | Ab 8 | Wh 8 (all f16)
// ---------------------------------------------------------------------------
extern "C" void kernel_launch(void* const* d_in, const int* in_sizes, int n_in,
                              void* d_out, int out_size, void* d_ws, size_t ws_size,
                              hipStream_t stream) {
    const float* x  = (const float*)d_in[0];
    const float* Wq = (const float*)d_in[1];
    const float* Wk = (const float*)d_in[2];
    const float* Wv = (const float*)d_in[3];
    const float* Wo = (const float*)d_in[4];
    float* out = (float*)d_out;

    const size_t NELEM = (size_t)MROWS * DMODEL;       // 4M
    const size_t WELEM = (size_t)DMODEL * DMODEL;      // 1M
    _Float16* Qh = (_Float16*)d_ws;
    _Float16* Kh = Qh + NELEM;
    _Float16* Vt = Kh + NELEM;                         // [b][h][d][s]
    _Float16* Ab = Vt + NELEM;
    _Float16* Wh = Ab + NELEM;

    // ---- weight conversion (f32 -> f16) ----
    const int wn8 = (int)(WELEM / 8);
    const int cvt_blocks = (wn8 + 255) / 256;
    cvt_f32_f16<<<cvt_blocks, 256, 0, stream>>>(Wq, Wh + 0 * WELEM, wn8);
    cvt_f32_f16<<<cvt_blocks, 256, 0, stream>>>(Wk, Wh + 1 * WELEM, wn8);
    cvt_f32_f16<<<cvt_blocks, 256, 0, stream>>>(Wv, Wh + 2 * WELEM, wn8);
    cvt_f32_f16<<<cvt_blocks, 256, 0, stream>>>(Wo, Wh + 3 * WELEM, wn8);

    // ---- projections ----
    const dim3 ggrid(DMODEL / GBN, MROWS / GBM);       // (16, 32)
    gemm_k<0,1><<<ggrid, 256, 0, stream>>>(x, Wh + 0 * WELEM, Qh);
    gemm_k<0,1><<<ggrid, 256, 0, stream>>>(x, Wh + 1 * WELEM, Kh);
    gemm_k<0,2><<<ggrid, 256, 0, stream>>>(x, Wh + 2 * WELEM, Vt);

    // ---- attention ----
    const dim3 agrid(SEQ / 64, BATCH * NHEADS);        // (32, 32)
    attn_mfma<<<agrid, 256, 0, stream>>>(Qh, Kh, Vt, Ab);

    // ---- output projection (f16 A, f32 out) ----
    gemm_k<1,0><<<ggrid, 256, 0, stream>>>(Ab, Wh + 3 * WELEM, out);
}

// Round 5
// 251.690 us; speedup vs baseline: 4.2860x; 1.2691x over previous
//
#include <hip/hip_runtime.h>
#include <math.h>

// Problem constants: SEQ=2048, BATCH=2, D_MODEL=1024, H=16, Hd=64
#define SEQ     2048
#define BATCH   2
#define DMODEL  1024
#define NHEADS  16
#define HDIM    64
#define MROWS   (SEQ * BATCH)
#define KDIM    1024

typedef _Float16 half8  __attribute__((ext_vector_type(8)));
typedef _Float16 half2v __attribute__((ext_vector_type(2)));
typedef float    f32x4  __attribute__((ext_vector_type(4)));

// ---------------------------------------------------------------------------
// async global->LDS, 16B per lane. LDS dest = wave-uniform base + lane*16.
// ---------------------------------------------------------------------------
__device__ inline void gload_lds16(const void* g, void* lds_uniform) {
    __builtin_amdgcn_global_load_lds(
        (const __attribute__((address_space(1))) void*)g,
        (__attribute__((address_space(3))) void*)lds_uniform,
        16, 0, 0);
}

// ---------------------------------------------------------------------------
// fp32 -> f16 conversion (weights; 1M elems per launch, 8 per thread)
// ---------------------------------------------------------------------------
__global__ __launch_bounds__(256)
void cvt_f32_f16(const float* __restrict__ s, _Float16* __restrict__ d, int n8) {
    const int i = blockIdx.x * 256 + threadIdx.x;
    if (i < n8) {
        const float4* sp = reinterpret_cast<const float4*>(s) + (size_t)i * 2;
        const float4 x0 = sp[0], x1 = sp[1];
        const half8 h = {(_Float16)x0.x, (_Float16)x0.y, (_Float16)x0.z, (_Float16)x0.w,
                         (_Float16)x1.x, (_Float16)x1.y, (_Float16)x1.z, (_Float16)x1.w};
        *(reinterpret_cast<half8*>(d) + i) = h;
    }
}

// ---------------------------------------------------------------------------
// GEMM: C[m][n] = sum_k A[m][k] * W[n][k].  M=4096, N=1024, K=1024.
// BM=128 BN=64, BK=64 as two 32-subtiles per barrier pair (16 MFMA/barrier).
// 256 threads = 4 waves (2x2), wave owns 64x32 out = 4x2 16x16 frags.
// AMODE: 0 = A fp32 (reg-stage + cvt), 1 = A f16.
// QKV=1: blockIdx.z selects weight 0..2; z 0,1 -> f16 rows (C0/C1),
//        z 2 -> V transposed to C2 = Vt[b][h][d][s].  QKV=0: f32 rows to C0.
// mfma_f32_16x16x32_f16 (m89-verified): A row=l&15, k=(l>>4)*8+j; B col=l&15;
// C/D col=l&15, row=(l>>4)*4+reg.
// ---------------------------------------------------------------------------
#define GBM 128
#define GBN 64

template<int AMODE, int QKV>
__global__ __launch_bounds__(256)
void gemm_k(const void* __restrict__ Ap, const _Float16* __restrict__ Wall,
            void* __restrict__ C0, void* __restrict__ C1, void* __restrict__ C2)
{
    __shared__ _Float16 As[2][GBM * 32];   // 2 x 8 KB
    __shared__ _Float16 Bs[2][GBN * 32];   // 2 x 4 KB

    const int tid  = threadIdx.x;
    const int wid  = tid >> 6;
    const int lane = tid & 63;
    const int m0 = blockIdx.y * GBM;
    const int n0 = blockIdx.x * GBN;
    const int wr = (wid >> 1) * 64;
    const int wc = (wid & 1) * 32;

    const _Float16* Wh = QKV ? (Wall + (size_t)blockIdx.z * KDIM * DMODEL) : Wall;

    const int a_row = tid >> 2;
    const int a_col = (tid & 3) * 8;          // k-elems (16B granule)
    const int b_row = wid * 16 + (lane >> 2);
    const int b_col = (lane & 3) * 8;

    const float*    Af0 = (const float*)Ap    + (size_t)(m0 + a_row)      * KDIM + a_col;
    const float*    Af1 = (const float*)Ap    + (size_t)(m0 + a_row + 64) * KDIM + a_col;
    const _Float16* Ah0 = (const _Float16*)Ap + (size_t)(m0 + a_row)      * KDIM + a_col;
    const _Float16* Ah1 = (const _Float16*)Ap + (size_t)(m0 + a_row + 64) * KDIM + a_col;
    const _Float16* Wr  = Wh + (size_t)(n0 + b_row) * KDIM + b_col;

    const int frow = lane & 15;
    const int kb   = (lane >> 4) * 8;

    f32x4 acc[4][2] = {};

    for (int k0 = 0; k0 < KDIM; k0 += 64) {
        #pragma unroll
        for (int s = 0; s < 2; ++s) {
            const int kk = k0 + s * 32;
            gload_lds16(Wr + kk, (char*)Bs[s] + wid * 1024);
            if constexpr (AMODE == 0) {
                const float4 a0 = *reinterpret_cast<const float4*>(Af0 + kk);
                const float4 a1 = *reinterpret_cast<const float4*>(Af0 + kk + 4);
                const float4 a2 = *reinterpret_cast<const float4*>(Af1 + kk);
                const float4 a3 = *reinterpret_cast<const float4*>(Af1 + kk + 4);
                const half8 h0 = {(_Float16)a0.x, (_Float16)a0.y, (_Float16)a0.z, (_Float16)a0.w,
                                  (_Float16)a1.x, (_Float16)a1.y, (_Float16)a1.z, (_Float16)a1.w};
                const half8 h1 = {(_Float16)a2.x, (_Float16)a2.y, (_Float16)a2.z, (_Float16)a2.w,
                                  (_Float16)a3.x, (_Float16)a3.y, (_Float16)a3.z, (_Float16)a3.w};
                *reinterpret_cast<half8*>((char*)As[s] + tid * 16)        = h0;
                *reinterpret_cast<half8*>((char*)As[s] + 4096 + tid * 16) = h1;
            } else {
                *reinterpret_cast<half8*>((char*)As[s] + tid * 16) =
                    *reinterpret_cast<const half8*>(Ah0 + kk);
                *reinterpret_cast<half8*>((char*)As[s] + 4096 + tid * 16) =
                    *reinterpret_cast<const half8*>(Ah1 + kk);
            }
        }
        __syncthreads();

        #pragma unroll
        for (int s = 0; s < 2; ++s) {
            half8 af[4], bf[2];
            #pragma unroll
            for (int fm = 0; fm < 4; ++fm)
                af[fm] = *reinterpret_cast<const half8*>(&As[s][(wr + fm * 16 + frow) * 32 + kb]);
            #pragma unroll
            for (int fn = 0; fn < 2; ++fn)
                bf[fn] = *reinterpret_cast<const half8*>(&Bs[s][(wc + fn * 16 + frow) * 32 + kb]);
            #pragma unroll
            for (int fm = 0; fm < 4; ++fm)
                #pragma unroll
                for (int fn = 0; fn < 2; ++fn)
                    acc[fm][fn] = __builtin_amdgcn_mfma_f32_16x16x32_f16(
                        af[fm], bf[fn], acc[fm][fn], 0, 0, 0);
        }
        __syncthreads();
    }

    const int crow = (lane >> 4) * 4;
    const int ccol = lane & 15;
    if constexpr (QKV == 0) {
        float* C = (float*)C0;
        #pragma unroll
        for (int fm = 0; fm < 4; ++fm)
            #pragma unroll
            for (int fn = 0; fn < 2; ++fn)
                #pragma unroll
                for (int r = 0; r < 4; ++r)
                    C[(size_t)(m0 + wr + fm * 16 + crow + r) * DMODEL
                      + n0 + wc + fn * 16 + ccol] = acc[fm][fn][r];
    } else {
        if (blockIdx.z < 2) {
            _Float16* C = (_Float16*)(blockIdx.z == 0 ? C0 : C1);
            #pragma unroll
            for (int fm = 0; fm < 4; ++fm)
                #pragma unroll
                for (int fn = 0; fn < 2; ++fn)
                    #pragma unroll
                    for (int r = 0; r < 4; ++r)
                        C[(size_t)(m0 + wr + fm * 16 + crow + r) * DMODEL
                          + n0 + wc + fn * 16 + ccol] = (_Float16)acc[fm][fn][r];
        } else {
            // V transpose. m = s*2+b; crow base even -> even r is b=0, odd r b=1.
            // h = blockIdx.x (GBN == HDIM). Vt[((b*16+h)*64+d)*SEQ + s].
            _Float16* Vt = (_Float16*)C2;
            const int hh = blockIdx.x;
            #pragma unroll
            for (int fm = 0; fm < 4; ++fm)
                #pragma unroll
                for (int fn = 0; fn < 2; ++fn) {
                    const int d  = wc + fn * 16 + ccol;
                    const int s0 = (m0 + wr + fm * 16 + crow) >> 1;
                    const half2v lo = {(_Float16)acc[fm][fn][0], (_Float16)acc[fm][fn][2]};
                    const half2v hi = {(_Float16)acc[fm][fn][1], (_Float16)acc[fm][fn][3]};
                    *reinterpret_cast<half2v*>(Vt + ((size_t)(hh * 64 + d)) * SEQ + s0) = lo;
                    *reinterpret_cast<half2v*>(Vt + ((size_t)((16 + hh) * 64 + d)) * SEQ + s0) = hi;
                }
        }
    }
}

// ---------------------------------------------------------------------------
// MFMA flash attention with causal load-balance pairing.
// Grid (16, 32): block processes q-tiles {bx, 31-bx} -> 33 KV-tile units per
// block, uniform across all 512 blocks (2 blocks/CU). 256 threads = 4 waves,
// wave w owns q-rows [q0 + w*16, +16). LDS tiles 64x64 f16, 128B rows,
// XOR-swizzled at 16B granularity (chunk ^= row&7) via pre-swizzled
// global_load_lds source. P via per-wave padded LDS (pitch 144B, no barrier).
// ---------------------------------------------------------------------------
__global__ __launch_bounds__(256)
void attn_mfma(const _Float16* __restrict__ Qh, const _Float16* __restrict__ Kh,
               const _Float16* __restrict__ Vt, _Float16* __restrict__ Ab)
{
    __shared__ _Float16 Qs[64 * 64];
    __shared__ _Float16 Ks[64 * 64];
    __shared__ _Float16 Vs[64 * 64];
    __shared__ _Float16 Ps[4 * 16 * 72];

    const int tid  = threadIdx.x;
    const int wid  = tid >> 6;
    const int lane = tid & 63;
    const int l4 = lane & 15, lg = lane >> 4;
    const int bh = blockIdx.y, b = bh >> 4, h = bh & 15;

    for (int half = 0; half < 2; ++half) {
        const int qt = half ? (31 - (int)blockIdx.x) : (int)blockIdx.x;
        const int q0 = qt * 64;

        __syncthreads();   // prev half's LDS readers done before Q restage
        #pragma unroll
        for (int i = 0; i < 2; ++i) {
            const int row = i * 32 + wid * 8 + (lane >> 3);
            const int c   = (lane & 7) ^ (row & 7);
            gload_lds16(Qh + ((size_t)((q0 + row) * 2 + b)) * DMODEL + h * 64 + c * 8,
                        (char*)Qs + i * 4096 + wid * 1024);
        }
        __syncthreads();

        half8 qf[2];
        {
            const int row = wid * 16 + l4;
            #pragma unroll
            for (int ks = 0; ks < 2; ++ks) {
                const int p = (ks * 4 + lg) ^ (row & 7);
                qf[ks] = *reinterpret_cast<const half8*>((char*)Qs + row * 128 + p * 16);
            }
        }

        float m_r[4], l_r[4];
        f32x4 o[4] = {};
        #pragma unroll
        for (int r = 0; r < 4; ++r) { m_r[r] = -1e30f; l_r[r] = 0.f; }

        _Float16* Pw = Ps + wid * 16 * 72;
        const int ktiles = qt + 1;

        for (int kt = 0; kt < ktiles; ++kt) {
            const int t0 = kt * 64;
            __syncthreads();
            #pragma unroll
            for (int i = 0; i < 2; ++i) {
                const int row = i * 32 + wid * 8 + (lane >> 3);
                const int c   = (lane & 7) ^ (row & 7);
                gload_lds16(Kh + ((size_t)((t0 + row) * 2 + b)) * DMODEL + h * 64 + c * 8,
                            (char*)Ks + i * 4096 + wid * 1024);
                gload_lds16(Vt + ((size_t)(bh * 64 + row)) * SEQ + t0 + c * 8,
                            (char*)Vs + i * 4096 + wid * 1024);
            }
            __syncthreads();

            // ---- S = Q K^T ----
            f32x4 sacc[4] = {};
            #pragma unroll
            for (int ks = 0; ks < 2; ++ks)
                #pragma unroll
                for (int fn = 0; fn < 4; ++fn) {
                    const int row = fn * 16 + l4;
                    const int p   = (ks * 4 + lg) ^ (row & 7);
                    const half8 bf = *reinterpret_cast<const half8*>((char*)Ks + row * 128 + p * 16);
                    sacc[fn] = __builtin_amdgcn_mfma_f32_16x16x32_f16(qf[ks], bf, sacc[fn], 0, 0, 0);
                }

            // ---- mask + online softmax (16-lane shfl reduce) ----
            const int qbase = q0 + wid * 16 + lg * 4;
            float sv[4][4];
            #pragma unroll
            for (int fn = 0; fn < 4; ++fn) {
                const int tg = t0 + fn * 16 + l4;
                #pragma unroll
                for (int r = 0; r < 4; ++r)
                    sv[fn][r] = (tg <= qbase + r) ? sacc[fn][r] * 0.125f : -1e30f;
            }
            #pragma unroll
            for (int r = 0; r < 4; ++r) {
                float rm = fmaxf(fmaxf(sv[0][r], sv[1][r]), fmaxf(sv[2][r], sv[3][r]));
                rm = fmaxf(rm, __shfl_xor(rm, 1));
                rm = fmaxf(rm, __shfl_xor(rm, 2));
                rm = fmaxf(rm, __shfl_xor(rm, 4));
                rm = fmaxf(rm, __shfl_xor(rm, 8));
                const float mnew  = fmaxf(m_r[r], rm);
                const float alpha = __expf(m_r[r] - mnew);
                m_r[r] = mnew;
                float rs = 0.f;
                #pragma unroll
                for (int fn = 0; fn < 4; ++fn) {
                    const float pv = __expf(sv[fn][r] - mnew);
                    sv[fn][r] = pv; rs += pv;
                }
                rs += __shfl_xor(rs, 1); rs += __shfl_xor(rs, 2);
                rs += __shfl_xor(rs, 4); rs += __shfl_xor(rs, 8);
                l_r[r] = l_r[r] * alpha + rs;
                #pragma unroll
                for (int fn = 0; fn < 4; ++fn) o[fn][r] *= alpha;
            }

            // ---- P -> f16 via per-wave padded LDS ----
            #pragma unroll
            for (int fn = 0; fn < 4; ++fn)
                #pragma unroll
                for (int r = 0; r < 4; ++r)
                    Pw[(lg * 4 + r) * 72 + fn * 16 + l4] = (_Float16)sv[fn][r];

            half8 pf[2];
            #pragma unroll
            for (int ks = 0; ks < 2; ++ks)
                pf[ks] = *reinterpret_cast<const half8*>((char*)Pw + l4 * 144 + ks * 64 + lg * 16);

            // ---- O += P V ----
            #pragma unroll
            for (int ks = 0; ks < 2; ++ks)
                #pragma unroll
                for (int fn = 0; fn < 4; ++fn) {
                    const int row = fn * 16 + l4;
                    const int p   = (ks * 4 + lg) ^ (row & 7);
                    const half8 vf = *reinterpret_cast<const half8*>((char*)Vs + row * 128 + p * 16);
                    o[fn] = __builtin_amdgcn_mfma_f32_16x16x32_f16(pf[ks], vf, o[fn], 0, 0, 0);
                }
        }

        // ---- normalize, store f16 rows ----
        #pragma unroll
        for (int r = 0; r < 4; ++r) {
            const float inv = 1.0f / l_r[r];
            const size_t mrow = (size_t)((q0 + wid * 16 + lg * 4 + r) * 2 + b);
            #pragma unroll
            for (int fn = 0; fn < 4; ++fn)
                Ab[mrow * DMODEL + h * 64 + fn * 16 + l4] = (_Float16)(o[fn][r] * inv);
        }
    }
}

// ---------------------------------------------------------------------------
// ws layout (40 MB): Qh 8 | Kh 8 | Vt 8 | Ab 8 | Wh 8 (all f16)
// ---------------------------------------------------------------------------
extern "C" void kernel_launch(void* const* d_in, const int* in_sizes, int n_in,
                              void* d_out, int out_size, void* d_ws, size_t ws_size,
                              hipStream_t stream) {
    const float* x  = (const float*)d_in[0];
    const float* Wq = (const float*)d_in[1];
    const float* Wk = (const float*)d_in[2];
    const float* Wv = (const float*)d_in[3];
    const float* Wo = (const float*)d_in[4];
    float* out = (float*)d_out;

    const size_t NELEM = (size_t)MROWS * DMODEL;       // 4M
    const size_t WELEM = (size_t)DMODEL * DMODEL;      // 1M
    _Float16* Qh = (_Float16*)d_ws;
    _Float16* Kh = Qh + NELEM;
    _Float16* Vt = Kh + NELEM;                         // [b][h][d][s]
    _Float16* Ab = Vt + NELEM;
    _Float16* Wh = Ab + NELEM;                         // Wq|Wk|Wv|Wo f16

    // ---- weight conversion (f32 -> f16) ----
    const int wn8 = (int)(WELEM / 8);
    const int cvt_blocks = (wn8 + 255) / 256;
    cvt_f32_f16<<<cvt_blocks, 256, 0, stream>>>(Wq, Wh + 0 * WELEM, wn8);
    cvt_f32_f16<<<cvt_blocks, 256, 0, stream>>>(Wk, Wh + 1 * WELEM, wn8);
    cvt_f32_f16<<<cvt_blocks, 256, 0, stream>>>(Wv, Wh + 2 * WELEM, wn8);
    cvt_f32_f16<<<cvt_blocks, 256, 0, stream>>>(Wo, Wh + 3 * WELEM, wn8);

    // ---- fused Q/K/V projections (z selects weight & epilogue) ----
    const dim3 qkv_grid(DMODEL / GBN, MROWS / GBM, 3); // (16, 32, 3)
    gemm_k<0,1><<<qkv_grid, 256, 0, stream>>>(x, Wh, Qh, Kh, Vt);

    // ---- attention (causal-paired, balanced) ----
    const dim3 agrid(SEQ / 128, BATCH * NHEADS);       // (16, 32)
    attn_mfma<<<agrid, 256, 0, stream>>>(Qh, Kh, Vt, Ab);

    // ---- output projection (f16 A, f32 out) ----
    const dim3 ogrid(DMODEL / GBN, MROWS / GBM);       // (16, 32)
    gemm_k<1,0><<<ogrid, 256, 0, stream>>>(Ab, Wh + 3 * WELEM, out, nullptr, nullptr);
}

// Round 9
// 218.369 us; speedup vs baseline: 4.9400x; 1.1526x over previous
//
#include <hip/hip_runtime.h>
#include <math.h>

// Problem constants: SEQ=2048, BATCH=2, D_MODEL=1024, H=16, Hd=64
#define SEQ     2048
#define BATCH   2
#define DMODEL  1024
#define NHEADS  16
#define HDIM    64
#define MROWS   (SEQ * BATCH)
#define KDIM    1024

typedef _Float16 half8  __attribute__((ext_vector_type(8)));
typedef _Float16 half2v __attribute__((ext_vector_type(2)));
typedef float    f32x4  __attribute__((ext_vector_type(4)));

// ---------------------------------------------------------------------------
// async global->LDS, 16B per lane. LDS dest = wave-uniform base + lane*16.
// ---------------------------------------------------------------------------
__device__ inline void gload_lds16(const void* g, void* lds_uniform) {
    __builtin_amdgcn_global_load_lds(
        (const __attribute__((address_space(1))) void*)g,
        (__attribute__((address_space(3))) void*)lds_uniform,
        16, 0, 0);
}

// ---------------------------------------------------------------------------
// fp32 -> f16 conversions. cvt_f32_f16: one tensor. cvt4: 4 weights batched
// (512 blocks each, wsel = blockIdx.x>>9).
// ---------------------------------------------------------------------------
__device__ inline void cvt8(const float* sp, _Float16* dp) {
    const float4 x0 = reinterpret_cast<const float4*>(sp)[0];
    const float4 x1 = reinterpret_cast<const float4*>(sp)[1];
    const half8 h = {(_Float16)x0.x, (_Float16)x0.y, (_Float16)x0.z, (_Float16)x0.w,
                     (_Float16)x1.x, (_Float16)x1.y, (_Float16)x1.z, (_Float16)x1.w};
    *reinterpret_cast<half8*>(dp) = h;
}

__global__ __launch_bounds__(256)
void cvt_f32_f16(const float* __restrict__ s, _Float16* __restrict__ d, int n8) {
    const int i = blockIdx.x * 256 + threadIdx.x;
    if (i < n8) cvt8(s + (size_t)i * 8, d + (size_t)i * 8);
}

__global__ __launch_bounds__(256)
void cvt4_w(const float* __restrict__ s0, const float* __restrict__ s1,
            const float* __restrict__ s2, const float* __restrict__ s3,
            _Float16* __restrict__ d) {
    const int wsel = blockIdx.x >> 9;                      // 512 blocks per weight
    const int i    = (blockIdx.x & 511) * 256 + threadIdx.x;  // 0..131071
    const float* s = (wsel == 0) ? s0 : (wsel == 1) ? s1 : (wsel == 2) ? s2 : s3;
    cvt8(s + (size_t)i * 8, d + (size_t)wsel * DMODEL * KDIM + (size_t)i * 8);
}

// ---------------------------------------------------------------------------
// GEMM: C[m][n] = sum_k A[m][k] * W[n][k], A and W both f16, staged via
// global_load_lds(16B) with XOR-swizzled source (LDS[row][j] = G[row][j^(row&7)],
// 128B rows -> conflict-free ds_read_b128 fragments). BM=128, BK=64,
// TBN in {64,128}. 256 threads = 4 waves (2x2); wave owns 64 x TBN/2.
// EPI=0: f32 rows to C0 (final proj). EPI=1: z=blockIdx.z selects weight;
// z 0,1 -> f16 rows (C0/C1); z 2 -> V transposed to C2 = Vt[b][h][d][s].
// mfma_f32_16x16x32_f16 (m89-verified): A row=l&15, k=(l>>4)*8+j; B col=l&15;
// C/D col=l&15, row=(l>>4)*4+reg.
// ---------------------------------------------------------------------------
template<int TBN, int EPI>
__global__ __launch_bounds__(256)
void gemm2(const _Float16* __restrict__ Ah, const _Float16* __restrict__ Wall,
           void* __restrict__ C0, void* __restrict__ C1, void* __restrict__ C2)
{
    constexpr int FN    = TBN / 32;      // 2 or 4 n-frags per wave
    constexpr int B_ISS = TBN / 32;      // 4KB stage issues for B tile
    __shared__ _Float16 As[128 * 64];    // 16 KB
    __shared__ _Float16 Bs[TBN * 64];    // 8 or 16 KB

    const int tid = threadIdx.x, wid = tid >> 6, lane = tid & 63;
    const int m0 = blockIdx.y * 128, n0 = blockIdx.x * TBN;
    const int wr = (wid >> 1) * 64, wc = (wid & 1) * (TBN / 2);
    const _Float16* Wh = EPI ? (Wall + (size_t)blockIdx.z * KDIM * DMODEL) : Wall;

    const int srow = wid * 8 + (lane >> 3);   // 0..31 within a stage issue
    const int sj   = lane & 7;                // raw chunk
    const int l4 = lane & 15, lg = lane >> 4;

    f32x4 acc[4][FN] = {};

    for (int k0 = 0; k0 < KDIM; k0 += 64) {
        #pragma unroll
        for (int i = 0; i < 4; ++i) {
            const int row = i * 32 + srow;
            const int c   = sj ^ (row & 7);
            gload_lds16(Ah + (size_t)(m0 + row) * KDIM + k0 + c * 8,
                        (char*)As + i * 4096 + wid * 1024);
        }
        #pragma unroll
        for (int i = 0; i < B_ISS; ++i) {
            const int row = i * 32 + srow;
            const int c   = sj ^ (row & 7);
            gload_lds16(Wh + (size_t)(n0 + row) * KDIM + k0 + c * 8,
                        (char*)Bs + i * 4096 + wid * 1024);
        }
        __syncthreads();

        #pragma unroll
        for (int ks = 0; ks < 2; ++ks) {
            half8 af[4], bf[FN];
            #pragma unroll
            for (int fm = 0; fm < 4; ++fm) {
                const int row = wr + fm * 16 + l4;
                const int p   = (ks * 4 + lg) ^ (row & 7);
                af[fm] = *reinterpret_cast<const half8*>((char*)As + row * 128 + p * 16);
            }
            #pragma unroll
            for (int fn = 0; fn < FN; ++fn) {
                const int row = wc + fn * 16 + l4;
                const int p   = (ks * 4 + lg) ^ (row & 7);
                bf[fn] = *reinterpret_cast<const half8*>((char*)Bs + row * 128 + p * 16);
            }
            #pragma unroll
            for (int fm = 0; fm < 4; ++fm)
                #pragma unroll
                for (int fn = 0; fn < FN; ++fn)
                    acc[fm][fn] = __builtin_amdgcn_mfma_f32_16x16x32_f16(
                        af[fm], bf[fn], acc[fm][fn], 0, 0, 0);
        }
        __syncthreads();
    }

    const int crow = lg * 4, ccol = l4;
    if constexpr (EPI == 0) {
        float* C = (float*)C0;
        #pragma unroll
        for (int fm = 0; fm < 4; ++fm)
            #pragma unroll
            for (int fn = 0; fn < FN; ++fn)
                #pragma unroll
                for (int r = 0; r < 4; ++r)
                    C[(size_t)(m0 + wr + fm * 16 + crow + r) * DMODEL
                      + n0 + wc + fn * 16 + ccol] = acc[fm][fn][r];
    } else {
        if (blockIdx.z < 2) {
            _Float16* C = (_Float16*)(blockIdx.z == 0 ? C0 : C1);
            #pragma unroll
            for (int fm = 0; fm < 4; ++fm)
                #pragma unroll
                for (int fn = 0; fn < FN; ++fn)
                    #pragma unroll
                    for (int r = 0; r < 4; ++r)
                        C[(size_t)(m0 + wr + fm * 16 + crow + r) * DMODEL
                          + n0 + wc + fn * 16 + ccol] = (_Float16)acc[fm][fn][r];
        } else {
            // V transpose: m = s*2+b, b = r&1 (base even). Vt[((b*16+h)*64+d)*SEQ+s].
            _Float16* Vt = (_Float16*)C2;
            #pragma unroll
            for (int fm = 0; fm < 4; ++fm)
                #pragma unroll
                for (int fn = 0; fn < FN; ++fn) {
                    const int ng = n0 + wc + fn * 16 + ccol;
                    const int hh = ng >> 6, d = ng & 63;
                    const int s0 = (m0 + wr + fm * 16 + crow) >> 1;
                    const half2v lo = {(_Float16)acc[fm][fn][0], (_Float16)acc[fm][fn][2]};
                    const half2v hi = {(_Float16)acc[fm][fn][1], (_Float16)acc[fm][fn][3]};
                    *reinterpret_cast<half2v*>(Vt + ((size_t)(hh * 64 + d)) * SEQ + s0) = lo;
                    *reinterpret_cast<half2v*>(Vt + ((size_t)((16 + hh) * 64 + d)) * SEQ + s0) = hi;
                }
        }
    }
}

// ---------------------------------------------------------------------------
// MFMA flash attention, causal-paired (block: q-tiles {bx, 31-bx} = 33 units),
// K/V double-buffered with prefetch: issue stage(kt+1) BEFORE computing kt;
// drain vmcnt + raw barrier once per tile (stage latency hides under compute).
// LDS 64x64 f16 tiles, 128B rows, XOR-swizzle (chunk ^= row&7) via
// pre-swizzled global source. P via per-wave padded LDS (pitch 144B).
// ---------------------------------------------------------------------------
__device__ inline void stage_kv(const _Float16* __restrict__ Kh,
                                const _Float16* __restrict__ Vt,
                                _Float16* KsBuf, _Float16* VsBuf,
                                int t0, int b, int bh, int h, int wid, int lane) {
    #pragma unroll
    for (int i = 0; i < 2; ++i) {
        const int row = i * 32 + wid * 8 + (lane >> 3);
        const int c   = (lane & 7) ^ (row & 7);
        gload_lds16(Kh + ((size_t)((t0 + row) * 2 + b)) * DMODEL + h * 64 + c * 8,
                    (char*)KsBuf + i * 4096 + wid * 1024);
        gload_lds16(Vt + ((size_t)(bh * 64 + row)) * SEQ + t0 + c * 8,
                    (char*)VsBuf + i * 4096 + wid * 1024);
    }
}

__global__ __launch_bounds__(256)
void attn_mfma(const _Float16* __restrict__ Qh, const _Float16* __restrict__ Kh,
               const _Float16* __restrict__ Vt, _Float16* __restrict__ Ab)
{
    __shared__ _Float16 Qs[64 * 64];
    __shared__ _Float16 Ks[2][64 * 64];
    __shared__ _Float16 Vs[2][64 * 64];
    __shared__ _Float16 Ps[4 * 16 * 72];

    const int tid  = threadIdx.x;
    const int wid  = tid >> 6;
    const int lane = tid & 63;
    const int l4 = lane & 15, lg = lane >> 4;
    const int bh = blockIdx.y, b = bh >> 4, h = bh & 15;

    for (int half = 0; half < 2; ++half) {
        const int qt = half ? (31 - (int)blockIdx.x) : (int)blockIdx.x;
        const int q0 = qt * 64;
        const int ktiles = qt + 1;

        __syncthreads();   // all waves done with prev half's LDS
        #pragma unroll
        for (int i = 0; i < 2; ++i) {
            const int row = i * 32 + wid * 8 + (lane >> 3);
            const int c   = (lane & 7) ^ (row & 7);
            gload_lds16(Qh + ((size_t)((q0 + row) * 2 + b)) * DMODEL + h * 64 + c * 8,
                        (char*)Qs + i * 4096 + wid * 1024);
        }
        stage_kv(Kh, Vt, Ks[0], Vs[0], 0, b, bh, h, wid, lane);
        __syncthreads();   // drains vmcnt: Qs + first K/V tile ready

        half8 qf[2];
        {
            const int row = wid * 16 + l4;
            #pragma unroll
            for (int ks = 0; ks < 2; ++ks) {
                const int p = (ks * 4 + lg) ^ (row & 7);
                qf[ks] = *reinterpret_cast<const half8*>((char*)Qs + row * 128 + p * 16);
            }
        }

        float m_r[4], l_r[4];
        f32x4 o[4] = {};
        #pragma unroll
        for (int r = 0; r < 4; ++r) { m_r[r] = -1e30f; l_r[r] = 0.f; }

        _Float16* Pw = Ps + wid * 16 * 72;

        for (int kt = 0; kt < ktiles; ++kt) {
            const int t0  = kt * 64;
            const int cur = kt & 1;

            // ---- prefetch next tile into the other buffer ----
            if (kt + 1 < ktiles)
                stage_kv(Kh, Vt, Ks[cur ^ 1], Vs[cur ^ 1], t0 + 64, b, bh, h, wid, lane);

            // ---- S = Q K^T (current buffer) ----
            f32x4 sacc[4] = {};
            #pragma unroll
            for (int ks = 0; ks < 2; ++ks)
                #pragma unroll
                for (int fn = 0; fn < 4; ++fn) {
                    const int row = fn * 16 + l4;
                    const int p   = (ks * 4 + lg) ^ (row & 7);
                    const half8 bf = *reinterpret_cast<const half8*>(
                        (char*)Ks[cur] + row * 128 + p * 16);
                    sacc[fn] = __builtin_amdgcn_mfma_f32_16x16x32_f16(qf[ks], bf, sacc[fn], 0, 0, 0);
                }

            // ---- mask + online softmax (16-lane shfl reduce) ----
            const int qbase = q0 + wid * 16 + lg * 4;
            float sv[4][4];
            #pragma unroll
            for (int fn = 0; fn < 4; ++fn) {
                const int tg = t0 + fn * 16 + l4;
                #pragma unroll
                for (int r = 0; r < 4; ++r)
                    sv[fn][r] = (tg <= qbase + r) ? sacc[fn][r] * 0.125f : -1e30f;
            }
            #pragma unroll
            for (int r = 0; r < 4; ++r) {
                float rm = fmaxf(fmaxf(sv[0][r], sv[1][r]), fmaxf(sv[2][r], sv[3][r]));
                rm = fmaxf(rm, __shfl_xor(rm, 1));
                rm = fmaxf(rm, __shfl_xor(rm, 2));
                rm = fmaxf(rm, __shfl_xor(rm, 4));
                rm = fmaxf(rm, __shfl_xor(rm, 8));
                const float mnew  = fmaxf(m_r[r], rm);
                const float alpha = __expf(m_r[r] - mnew);
                m_r[r] = mnew;
                float rs = 0.f;
                #pragma unroll
                for (int fn = 0; fn < 4; ++fn) {
                    const float pv = __expf(sv[fn][r] - mnew);
                    sv[fn][r] = pv; rs += pv;
                }
                rs += __shfl_xor(rs, 1); rs += __shfl_xor(rs, 2);
                rs += __shfl_xor(rs, 4); rs += __shfl_xor(rs, 8);
                l_r[r] = l_r[r] * alpha + rs;
                #pragma unroll
                for (int fn = 0; fn < 4; ++fn) o[fn][r] *= alpha;
            }

            // ---- P -> f16 via per-wave padded LDS (same-wave lgkm order) ----
            #pragma unroll
            for (int fn = 0; fn < 4; ++fn)
                #pragma unroll
                for (int r = 0; r < 4; ++r)
                    Pw[(lg * 4 + r) * 72 + fn * 16 + l4] = (_Float16)sv[fn][r];

            half8 pf[2];
            #pragma unroll
            for (int ks = 0; ks < 2; ++ks)
                pf[ks] = *reinterpret_cast<const half8*>((char*)Pw + l4 * 144 + ks * 64 + lg * 16);

            // ---- O += P V ----
            #pragma unroll
            for (int ks = 0; ks < 2; ++ks)
                #pragma unroll
                for (int fn = 0; fn < 4; ++fn) {
                    const int row = fn * 16 + l4;
                    const int p   = (ks * 4 + lg) ^ (row & 7);
                    const half8 vf = *reinterpret_cast<const half8*>(
                        (char*)Vs[cur] + row * 128 + p * 16);
                    o[fn] = __builtin_amdgcn_mfma_f32_16x16x32_f16(pf[ks], vf, o[fn], 0, 0, 0);
                }

            // ---- tile fence: prefetch landed, everyone done with cur ----
            asm volatile("s_waitcnt vmcnt(0)" ::: "memory");
            __builtin_amdgcn_s_barrier();
            __builtin_amdgcn_sched_barrier(0);
        }

        // ---- normalize, store f16 rows ----
        #pragma unroll
        for (int r = 0; r < 4; ++r) {
            const float inv = 1.0f / l_r[r];
            const size_t mrow = (size_t)((q0 + wid * 16 + lg * 4 + r) * 2 + b);
            #pragma unroll
            for (int fn = 0; fn < 4; ++fn)
                Ab[mrow * DMODEL + h * 64 + fn * 16 + l4] = (_Float16)(o[fn][r] * inv);
        }
    }
}

// ---------------------------------------------------------------------------
// ws layout (40 MB f16): Qh | Kh | Vt | AbXh (x-f16 overlaid with attn out) | Wh
// x-f16 is dead once QKV is done; attn then writes Ab into the same region.
// ---------------------------------------------------------------------------
extern "C" void kernel_launch(void* const* d_in, const int* in_sizes, int n_in,
                              void* d_out, int out_size, void* d_ws, size_t ws_size,
                              hipStream_t stream) {
    const float* x  = (const float*)d_in[0];
    const float* Wq = (const float*)d_in[1];
    const float* Wk = (const float*)d_in[2];
    const float* Wv = (const float*)d_in[3];
    const float* Wo = (const float*)d_in[4];
    float* out = (float*)d_out;

    const size_t NELEM = (size_t)MROWS * DMODEL;       // 4M
    const size_t WELEM = (size_t)DMODEL * DMODEL;      // 1M
    _Float16* Qh   = (_Float16*)d_ws;
    _Float16* Kh   = Qh + NELEM;
    _Float16* Vt   = Kh + NELEM;                       // [b][h][d][s]
    _Float16* AbXh = Vt + NELEM;                       // x-f16, later attn out
    _Float16* Wh   = AbXh + NELEM;                     // Wq|Wk|Wv|Wo f16

    // ---- conversions ----
    cvt_f32_f16<<<(int)(NELEM / 8 / 256), 256, 0, stream>>>(x, AbXh, (int)(NELEM / 8));
    cvt4_w<<<2048, 256, 0, stream>>>(Wq, Wk, Wv, Wo, Wh);

    // ---- fused Q/K/V projections (128x128 tile, z selects weight/epilogue) ----
    const dim3 qkv_grid(DMODEL / 128, MROWS / 128, 3); // (8, 32, 3) = 768
    gemm2<128, 1><<<qkv_grid, 256, 0, stream>>>(AbXh, Wh, Qh, Kh, Vt);

    // ---- attention (causal-paired, prefetch-pipelined) ----
    const dim3 agrid(SEQ / 128, BATCH * NHEADS);       // (16, 32) = 512
    attn_mfma<<<agrid, 256, 0, stream>>>(Qh, Kh, Vt, AbXh);

    // ---- output projection (128x64 tile, f32 out) ----
    const dim3 ogrid(DMODEL / 64, MROWS / 128);        // (16, 32) = 512
    gemm2<64, 0><<<ogrid, 256, 0, stream>>>(AbXh, Wh + 3 * WELEM, out, nullptr, nullptr);
}

// Round 11
// 212.353 us; speedup vs baseline: 5.0800x; 1.0283x over previous
//
#include <hip/hip_runtime.h>
#include <math.h>

// Problem constants: SEQ=2048, BATCH=2, D_MODEL=1024, H=16, Hd=64
#define SEQ     2048
#define BATCH   2
#define DMODEL  1024
#define NHEADS  16
#define HDIM    64
#define MROWS   (SEQ * BATCH)
#define KDIM    1024

typedef _Float16 half8  __attribute__((ext_vector_type(8)));
typedef _Float16 half2v __attribute__((ext_vector_type(2)));
typedef float    f32x4  __attribute__((ext_vector_type(4)));

// ---------------------------------------------------------------------------
// async global->LDS, 16B per lane. LDS dest = wave-uniform base + lane*16.
// ---------------------------------------------------------------------------
__device__ inline void gload_lds16(const void* g, void* lds_uniform) {
    __builtin_amdgcn_global_load_lds(
        (const __attribute__((address_space(1))) void*)g,
        (__attribute__((address_space(3))) void*)lds_uniform,
        16, 0, 0);
}

// ---------------------------------------------------------------------------
// fp32 -> f16 conversions. cvt_f32_f16: one tensor. cvt4: 4 weights batched
// (512 blocks each, wsel = blockIdx.x>>9).
// ---------------------------------------------------------------------------
__device__ inline void cvt8(const float* sp, _Float16* dp) {
    const float4 x0 = reinterpret_cast<const float4*>(sp)[0];
    const float4 x1 = reinterpret_cast<const float4*>(sp)[1];
    const half8 h = {(_Float16)x0.x, (_Float16)x0.y, (_Float16)x0.z, (_Float16)x0.w,
                     (_Float16)x1.x, (_Float16)x1.y, (_Float16)x1.z, (_Float16)x1.w};
    *reinterpret_cast<half8*>(dp) = h;
}

__global__ __launch_bounds__(256)
void cvt_f32_f16(const float* __restrict__ s, _Float16* __restrict__ d, int n8) {
    const int i = blockIdx.x * 256 + threadIdx.x;
    if (i < n8) cvt8(s + (size_t)i * 8, d + (size_t)i * 8);
}

__global__ __launch_bounds__(256)
void cvt4_w(const float* __restrict__ s0, const float* __restrict__ s1,
            const float* __restrict__ s2, const float* __restrict__ s3,
            _Float16* __restrict__ d) {
    const int wsel = blockIdx.x >> 9;                      // 512 blocks per weight
    const int i    = (blockIdx.x & 511) * 256 + threadIdx.x;  // 0..131071
    const float* s = (wsel == 0) ? s0 : (wsel == 1) ? s1 : (wsel == 2) ? s2 : s3;
    cvt8(s + (size_t)i * 8, d + (size_t)wsel * DMODEL * KDIM + (size_t)i * 8);
}

// ---------------------------------------------------------------------------
// GEMM: C[m][n] = sum_k A[m][k] * W[n][k], A and W both f16, staged via
// global_load_lds(16B) with XOR-swizzled source (LDS[row][j] = G[row][j^(row&7)],
// 128B rows -> conflict-free ds_read_b128 fragments). BM=128, BK=64,
// TBN in {64,128}. 256 threads = 4 waves (2x2); wave owns 64 x TBN/2.
// EPI=0: f32 rows to C0 (final proj). EPI=1: z=blockIdx.z selects weight;
// z 0,1 -> f16 rows (C0/C1); z 2 -> V transposed to C2 = Vt[b][h][d][s].
// UNCHANGED (validated round 9) — counters surface next round.
// ---------------------------------------------------------------------------
template<int TBN, int EPI>
__global__ __launch_bounds__(256)
void gemm2(const _Float16* __restrict__ Ah, const _Float16* __restrict__ Wall,
           void* __restrict__ C0, void* __restrict__ C1, void* __restrict__ C2)
{
    constexpr int FN    = TBN / 32;
    constexpr int B_ISS = TBN / 32;
    __shared__ _Float16 As[128 * 64];
    __shared__ _Float16 Bs[TBN * 64];

    const int tid = threadIdx.x, wid = tid >> 6, lane = tid & 63;
    const int m0 = blockIdx.y * 128, n0 = blockIdx.x * TBN;
    const int wr = (wid >> 1) * 64, wc = (wid & 1) * (TBN / 2);
    const _Float16* Wh = EPI ? (Wall + (size_t)blockIdx.z * KDIM * DMODEL) : Wall;

    const int srow = wid * 8 + (lane >> 3);
    const int sj   = lane & 7;
    const int l4 = lane & 15, lg = lane >> 4;

    f32x4 acc[4][FN] = {};

    for (int k0 = 0; k0 < KDIM; k0 += 64) {
        #pragma unroll
        for (int i = 0; i < 4; ++i) {
            const int row = i * 32 + srow;
            const int c   = sj ^ (row & 7);
            gload_lds16(Ah + (size_t)(m0 + row) * KDIM + k0 + c * 8,
                        (char*)As + i * 4096 + wid * 1024);
        }
        #pragma unroll
        for (int i = 0; i < B_ISS; ++i) {
            const int row = i * 32 + srow;
            const int c   = sj ^ (row & 7);
            gload_lds16(Wh + (size_t)(n0 + row) * KDIM + k0 + c * 8,
                        (char*)Bs + i * 4096 + wid * 1024);
        }
        __syncthreads();

        #pragma unroll
        for (int ks = 0; ks < 2; ++ks) {
            half8 af[4], bf[FN];
            #pragma unroll
            for (int fm = 0; fm < 4; ++fm) {
                const int row = wr + fm * 16 + l4;
                const int p   = (ks * 4 + lg) ^ (row & 7);
                af[fm] = *reinterpret_cast<const half8*>((char*)As + row * 128 + p * 16);
            }
            #pragma unroll
            for (int fn = 0; fn < FN; ++fn) {
                const int row = wc + fn * 16 + l4;
                const int p   = (ks * 4 + lg) ^ (row & 7);
                bf[fn] = *reinterpret_cast<const half8*>((char*)Bs + row * 128 + p * 16);
            }
            #pragma unroll
            for (int fm = 0; fm < 4; ++fm)
                #pragma unroll
                for (int fn = 0; fn < FN; ++fn)
                    acc[fm][fn] = __builtin_amdgcn_mfma_f32_16x16x32_f16(
                        af[fm], bf[fn], acc[fm][fn], 0, 0, 0);
        }
        __syncthreads();
    }

    const int crow = lg * 4, ccol = l4;
    if constexpr (EPI == 0) {
        float* C = (float*)C0;
        #pragma unroll
        for (int fm = 0; fm < 4; ++fm)
            #pragma unroll
            for (int fn = 0; fn < FN; ++fn)
                #pragma unroll
                for (int r = 0; r < 4; ++r)
                    C[(size_t)(m0 + wr + fm * 16 + crow + r) * DMODEL
                      + n0 + wc + fn * 16 + ccol] = acc[fm][fn][r];
    } else {
        if (blockIdx.z < 2) {
            _Float16* C = (_Float16*)(blockIdx.z == 0 ? C0 : C1);
            #pragma unroll
            for (int fm = 0; fm < 4; ++fm)
                #pragma unroll
                for (int fn = 0; fn < FN; ++fn)
                    #pragma unroll
                    for (int r = 0; r < 4; ++r)
                        C[(size_t)(m0 + wr + fm * 16 + crow + r) * DMODEL
                          + n0 + wc + fn * 16 + ccol] = (_Float16)acc[fm][fn][r];
        } else {
            // V transpose: m = s*2+b, b = r&1 (base even). Vt[((b*16+h)*64+d)*SEQ+s].
            _Float16* Vt = (_Float16*)C2;
            #pragma unroll
            for (int fm = 0; fm < 4; ++fm)
                #pragma unroll
                for (int fn = 0; fn < FN; ++fn) {
                    const int ng = n0 + wc + fn * 16 + ccol;
                    const int hh = ng >> 6, d = ng & 63;
                    const int s0 = (m0 + wr + fm * 16 + crow) >> 1;
                    const half2v lo = {(_Float16)acc[fm][fn][0], (_Float16)acc[fm][fn][2]};
                    const half2v hi = {(_Float16)acc[fm][fn][1], (_Float16)acc[fm][fn][3]};
                    *reinterpret_cast<half2v*>(Vt + ((size_t)(hh * 64 + d)) * SEQ + s0) = lo;
                    *reinterpret_cast<half2v*>(Vt + ((size_t)((16 + hh) * 64 + d)) * SEQ + s0) = hi;
                }
        }
    }
}

// ---------------------------------------------------------------------------
// MFMA flash attention. 1024-block balanced flat grid, ONE q-tile per block:
//   id -> r=id&255, g=id>>8; bh=r&31, x5=r>>5, s=g*8+x5,
//   qt = s<16 ? s : 47-s   (bijection 0..31)
// Under round-robin id%256 CU placement each CU gets qt-set
// {x5, x5+8, 31-x5, 23-x5}: ktiles sum = 66 (uniform) and same bh (KV L2-hot).
// 50 KB LDS -> 3 blocks/CU resident = 12 waves/CU (was 8).
// K/V double-buffered with prefetch-before-compute; vmcnt(0)+s_barrier fence
// per tile (validated r9). T5 setprio(1) around MFMA clusters.
// ---------------------------------------------------------------------------
__device__ inline void stage_kv(const _Float16* __restrict__ Kh,
                                const _Float16* __restrict__ Vt,
                                _Float16* KsBuf, _Float16* VsBuf,
                                int t0, int b, int bh, int h, int wid, int lane) {
    #pragma unroll
    for (int i = 0; i < 2; ++i) {
        const int row = i * 32 + wid * 8 + (lane >> 3);
        const int c   = (lane & 7) ^ (row & 7);
        gload_lds16(Kh + ((size_t)((t0 + row) * 2 + b)) * DMODEL + h * 64 + c * 8,
                    (char*)KsBuf + i * 4096 + wid * 1024);
        gload_lds16(Vt + ((size_t)(bh * 64 + row)) * SEQ + t0 + c * 8,
                    (char*)VsBuf + i * 4096 + wid * 1024);
    }
}

__global__ __launch_bounds__(256)
void attn_mfma(const _Float16* __restrict__ Qh, const _Float16* __restrict__ Kh,
               const _Float16* __restrict__ Vt, _Float16* __restrict__ Ab)
{
    __shared__ _Float16 Qs[64 * 64];
    __shared__ _Float16 Ks[2][64 * 64];
    __shared__ _Float16 Vs[2][64 * 64];
    __shared__ _Float16 Ps[4 * 16 * 72];

    const int tid  = threadIdx.x;
    const int wid  = tid >> 6;
    const int lane = tid & 63;
    const int l4 = lane & 15, lg = lane >> 4;

    // balanced flat-grid mapping
    const int id = blockIdx.x;
    const int rr = id & 255, g = id >> 8;
    const int bh = rr & 31, x5 = rr >> 5;
    const int sidx = g * 8 + x5;
    const int qt = (sidx < 16) ? sidx : (47 - sidx);
    const int b = bh >> 4, h = bh & 15;
    const int q0 = qt * 64;
    const int ktiles = qt + 1;

    // ---- stage Q + first K/V tile ----
    #pragma unroll
    for (int i = 0; i < 2; ++i) {
        const int row = i * 32 + wid * 8 + (lane >> 3);
        const int c   = (lane & 7) ^ (row & 7);
        gload_lds16(Qh + ((size_t)((q0 + row) * 2 + b)) * DMODEL + h * 64 + c * 8,
                    (char*)Qs + i * 4096 + wid * 1024);
    }
    stage_kv(Kh, Vt, Ks[0], Vs[0], 0, b, bh, h, wid, lane);
    __syncthreads();   // drains vmcnt: Qs + first K/V ready

    half8 qf[2];
    {
        const int row = wid * 16 + l4;
        #pragma unroll
        for (int ks = 0; ks < 2; ++ks) {
            const int p = (ks * 4 + lg) ^ (row & 7);
            qf[ks] = *reinterpret_cast<const half8*>((char*)Qs + row * 128 + p * 16);
        }
    }

    float m_r[4], l_r[4];
    f32x4 o[4] = {};
    #pragma unroll
    for (int r = 0; r < 4; ++r) { m_r[r] = -1e30f; l_r[r] = 0.f; }

    _Float16* Pw = Ps + wid * 16 * 72;

    for (int kt = 0; kt < ktiles; ++kt) {
        const int t0  = kt * 64;
        const int cur = kt & 1;

        // ---- prefetch next tile into the other buffer ----
        if (kt + 1 < ktiles)
            stage_kv(Kh, Vt, Ks[cur ^ 1], Vs[cur ^ 1], t0 + 64, b, bh, h, wid, lane);

        // ---- S = Q K^T (current buffer) ----
        f32x4 sacc[4] = {};
        __builtin_amdgcn_s_setprio(1);
        #pragma unroll
        for (int ks = 0; ks < 2; ++ks)
            #pragma unroll
            for (int fn = 0; fn < 4; ++fn) {
                const int row = fn * 16 + l4;
                const int p   = (ks * 4 + lg) ^ (row & 7);
                const half8 bf = *reinterpret_cast<const half8*>(
                    (char*)Ks[cur] + row * 128 + p * 16);
                sacc[fn] = __builtin_amdgcn_mfma_f32_16x16x32_f16(qf[ks], bf, sacc[fn], 0, 0, 0);
            }
        __builtin_amdgcn_s_setprio(0);

        // ---- mask + online softmax (16-lane shfl reduce) ----
        const int qbase = q0 + wid * 16 + lg * 4;
        float sv[4][4];
        #pragma unroll
        for (int fn = 0; fn < 4; ++fn) {
            const int tg = t0 + fn * 16 + l4;
            #pragma unroll
            for (int r = 0; r < 4; ++r)
                sv[fn][r] = (tg <= qbase + r) ? sacc[fn][r] * 0.125f : -1e30f;
        }
        #pragma unroll
        for (int r = 0; r < 4; ++r) {
            float rm = fmaxf(fmaxf(sv[0][r], sv[1][r]), fmaxf(sv[2][r], sv[3][r]));
            rm = fmaxf(rm, __shfl_xor(rm, 1));
            rm = fmaxf(rm, __shfl_xor(rm, 2));
            rm = fmaxf(rm, __shfl_xor(rm, 4));
            rm = fmaxf(rm, __shfl_xor(rm, 8));
            const float mnew  = fmaxf(m_r[r], rm);
            const float alpha = __expf(m_r[r] - mnew);
            m_r[r] = mnew;
            float rs = 0.f;
            #pragma unroll
            for (int fn = 0; fn < 4; ++fn) {
                const float pv = __expf(sv[fn][r] - mnew);
                sv[fn][r] = pv; rs += pv;
            }
            rs += __shfl_xor(rs, 1); rs += __shfl_xor(rs, 2);
            rs += __shfl_xor(rs, 4); rs += __shfl_xor(rs, 8);
            l_r[r] = l_r[r] * alpha + rs;
            #pragma unroll
            for (int fn = 0; fn < 4; ++fn) o[fn][r] *= alpha;
        }

        // ---- P -> f16 via per-wave padded LDS (same-wave lgkm order) ----
        #pragma unroll
        for (int fn = 0; fn < 4; ++fn)
            #pragma unroll
            for (int r = 0; r < 4; ++r)
                Pw[(lg * 4 + r) * 72 + fn * 16 + l4] = (_Float16)sv[fn][r];

        half8 pf[2];
        #pragma unroll
        for (int ks = 0; ks < 2; ++ks)
            pf[ks] = *reinterpret_cast<const half8*>((char*)Pw + l4 * 144 + ks * 64 + lg * 16);

        // ---- O += P V ----
        __builtin_amdgcn_s_setprio(1);
        #pragma unroll
        for (int ks = 0; ks < 2; ++ks)
            #pragma unroll
            for (int fn = 0; fn < 4; ++fn) {
                const int row = fn * 16 + l4;
                const int p   = (ks * 4 + lg) ^ (row & 7);
                const half8 vf = *reinterpret_cast<const half8*>(
                    (char*)Vs[cur] + row * 128 + p * 16);
                o[fn] = __builtin_amdgcn_mfma_f32_16x16x32_f16(pf[ks], vf, o[fn], 0, 0, 0);
            }
        __builtin_amdgcn_s_setprio(0);

        // ---- tile fence: prefetch landed, everyone done with cur ----
        asm volatile("s_waitcnt vmcnt(0)" ::: "memory");
        __builtin_amdgcn_s_barrier();
        __builtin_amdgcn_sched_barrier(0);
    }

    // ---- normalize, store f16 rows ----
    #pragma unroll
    for (int r = 0; r < 4; ++r) {
        const float inv = 1.0f / l_r[r];
        const size_t mrow = (size_t)((q0 + wid * 16 + lg * 4 + r) * 2 + b);
        #pragma unroll
        for (int fn = 0; fn < 4; ++fn)
            Ab[mrow * DMODEL + h * 64 + fn * 16 + l4] = (_Float16)(o[fn][r] * inv);
    }
}

// ---------------------------------------------------------------------------
// ws layout (40 MB f16): Qh | Kh | Vt | AbXh (x-f16 overlaid with attn out) | Wh
// x-f16 is dead once QKV is done; attn then writes Ab into the same region.
// ---------------------------------------------------------------------------
extern "C" void kernel_launch(void* const* d_in, const int* in_sizes, int n_in,
                              void* d_out, int out_size, void* d_ws, size_t ws_size,
                              hipStream_t stream) {
    const float* x  = (const float*)d_in[0];
    const float* Wq = (const float*)d_in[1];
    const float* Wk = (const float*)d_in[2];
    const float* Wv = (const float*)d_in[3];
    const float* Wo = (const float*)d_in[4];
    float* out = (float*)d_out;

    const size_t NELEM = (size_t)MROWS * DMODEL;       // 4M
    const size_t WELEM = (size_t)DMODEL * DMODEL;      // 1M
    _Float16* Qh   = (_Float16*)d_ws;
    _Float16* Kh   = Qh + NELEM;
    _Float16* Vt   = Kh + NELEM;                       // [b][h][d][s]
    _Float16* AbXh = Vt + NELEM;                       // x-f16, later attn out
    _Float16* Wh   = AbXh + NELEM;                     // Wq|Wk|Wv|Wo f16

    // ---- conversions ----
    cvt_f32_f16<<<(int)(NELEM / 8 / 256), 256, 0, stream>>>(x, AbXh, (int)(NELEM / 8));
    cvt4_w<<<2048, 256, 0, stream>>>(Wq, Wk, Wv, Wo, Wh);

    // ---- fused Q/K/V projections (128x128 tile, z selects weight/epilogue) ----
    const dim3 qkv_grid(DMODEL / 128, MROWS / 128, 3); // (8, 32, 3) = 768
    gemm2<128, 1><<<qkv_grid, 256, 0, stream>>>(AbXh, Wh, Qh, Kh, Vt);

    // ---- attention (1024-block balanced flat grid) ----
    attn_mfma<<<1024, 256, 0, stream>>>(Qh, Kh, Vt, AbXh);

    // ---- output projection (128x64 tile, f32 out) ----
    const dim3 ogrid(DMODEL / 64, MROWS / 128);        // (16, 32) = 512
    gemm2<64, 0><<<ogrid, 256, 0, stream>>>(AbXh, Wh + 3 * WELEM, out, nullptr, nullptr);
}